// Round 4
// baseline (646.072 us; speedup 1.0000x reference)
//
#include <hip/hip_runtime.h>
#include <math.h>

#define NA 10000
#define NE 250000
#define FD 128
#define NRBF 20
#define RCUT 5.0f
#define EDGE_GRID 4096

typedef _Float16 h16;
typedef __attribute__((ext_vector_type(8))) _Float16 half8;
typedef __attribute__((ext_vector_type(2))) _Float16 half2v;
typedef __attribute__((ext_vector_type(4))) float f32x4;

static __device__ __forceinline__ half8 f32x8_to_h8(const float* p) {
    float4 a = *(const float4*)p;
    float4 b = *(const float4*)(p + 4);
    half8 r;
    r[0] = (h16)a.x; r[1] = (h16)a.y; r[2] = (h16)a.z; r[3] = (h16)a.w;
    r[4] = (h16)b.x; r[5] = (h16)b.y; r[6] = (h16)b.z; r[7] = (h16)b.w;
    return r;
}
static __device__ __forceinline__ float silu(float v) {
    return v / (1.f + expf(-v));
}

// ====== mega setup: geom | csr | weight transposes | filter prep ======
// ed[e] = one 64B row: 24 h16 (20 gauss*fcut, fcut, 3 zero) + float4 dir.
__global__ __launch_bounds__(256) void setup_kernel(
    const float* __restrict__ R, const int* __restrict__ idx_i,
    const int* __restrict__ idx_j, const float* __restrict__ offsets,
    h16* __restrict__ ed, int* __restrict__ row_start,
    const float* __restrict__ int_W1, const float* __restrict__ int_W2,
    const float* __restrict__ mix_Wmu, const float* __restrict__ mix_W1,
    const float* __restrict__ mix_W2,
    h16* __restrict__ W1t, h16* __restrict__ W2t, h16* __restrict__ WmuT,
    h16* __restrict__ mW1t, h16* __restrict__ mW2t,
    const float* __restrict__ filt_W, const float* __restrict__ filt_b,
    h16* __restrict__ fwt, int* __restrict__ ctr)
{
    const int b = blockIdx.x;
    if (b == 0 && threadIdx.x < 4) ctr[threadIdx.x] = EDGE_GRID;
    if (b < 977) {
        int e = b * 256 + threadIdx.x;
        if (e >= NE) return;
        int i = idx_i[e], j = idx_j[e];
        float rx = R[j * 3 + 0] - R[i * 3 + 0] + offsets[e * 3 + 0];
        float ry = R[j * 3 + 1] - R[i * 3 + 1] + offsets[e * 3 + 1];
        float rz = R[j * 3 + 2] - R[i * 3 + 2] + offsets[e * 3 + 2];
        float d = sqrtf(rx * rx + ry * ry + rz * rz);
        float inv = 1.f / d;
        float fcut = 0.f;
        if (d < RCUT) fcut = 0.5f * (cosf(d * (3.14159265358979323846f / RCUT)) + 1.f);
        h16* pp = ed + (size_t)e * 32;
        const float delta = RCUT / 19.f;
        const float coeff = -0.5f / (delta * delta);
#pragma unroll
        for (int r = 0; r < NRBF; ++r) {
            float dc = d - (float)r * delta;
            pp[r] = (h16)(expf(coeff * dc * dc) * fcut);
        }
        pp[20] = (h16)fcut;
        pp[21] = (h16)0.f; pp[22] = (h16)0.f; pp[23] = (h16)0.f;
        *(float4*)(pp + 24) = make_float4(rx * inv, ry * inv, rz * inv, 0.f);
    } else if (b < 1017) {
        int n = (b - 977) * 256 + threadIdx.x;
        if (n > NA) return;
        int lo = 0, hi = NE;
        while (lo < hi) {
            int mid = (lo + hi) >> 1;
            if (idx_i[mid] < n) lo = mid + 1; else hi = mid;
        }
        row_start[n] = lo;
    } else {
        int idx = (b - 1017) * 256 + threadIdx.x;
        if (idx < 49152) {                       // int_W1: K=128,N=128
            int bt = idx >> 14, rem = idx & 16383;
            int nn = rem >> 7, kk = rem & 127;
            W1t[idx] = (h16)int_W1[(size_t)bt * 16384 + kk * 128 + nn];
        } else if ((idx -= 49152) < 147456) {    // int_W2: K=128,N=384
            int bt = idx / 49152, rem = idx - bt * 49152;
            int nn = rem >> 7, kk = rem & 127;
            W2t[idx] = (h16)int_W2[(size_t)bt * 49152 + kk * 384 + nn];
        } else if ((idx -= 147456) < 98304) {    // mix_Wmu: K=128,N=256
            int bt = idx >> 15, rem = idx & 32767;
            int nn = rem >> 7, kk = rem & 127;
            WmuT[idx] = (h16)mix_Wmu[(size_t)bt * 32768 + kk * 256 + nn];
        } else if ((idx -= 98304) < 98304) {     // mix_W1: K=256,N=128
            int bt = idx >> 15, rem = idx & 32767;
            int nn = rem >> 8, kk = rem & 255;
            mW1t[idx] = (h16)mix_W1[(size_t)bt * 32768 + kk * 128 + nn];
        } else if ((idx -= 98304) < 147456) {    // mix_W2: K=128,N=384
            int bt = idx / 49152, rem = idx - bt * 49152;
            int nn = rem >> 7, kk = rem & 127;
            mW2t[idx] = (h16)mix_W2[(size_t)bt * 49152 + kk * 384 + nn];
        } else if ((idx -= 147456) < 12288) {    // fwt [384][32]
            int nn = idx >> 5, kk = idx & 31;
            float v = 0.f;
            if (kk < 20) v = filt_W[kk * 384 + nn];
            else if (kk == 20) v = filt_b[nn];
            fwt[idx] = (h16)v;
        }
    }
}

// ====== iteration-0 interaction MLP: q = emb[Z]; x = silu(q@W1+b1)@W2+b2 ==
__global__ __launch_bounds__(256) void intmlp0_kernel(
    const int* __restrict__ Z, const float* __restrict__ emb, float* __restrict__ q,
    const h16* __restrict__ W1t, const float* __restrict__ b1,
    const h16* __restrict__ W2t, const float* __restrict__ b2, h16* __restrict__ xm)
{
    __shared__ h16 Hs[16 * 136];
    __shared__ __align__(16) h16 XMP[16 * 128 * 6];
    const int tid = threadIdx.x;
    const int wave = tid >> 6, lane = tid & 63;
    const int ar = lane & 15, kg = lane >> 4;
    const size_t row0 = (size_t)blockIdx.x * 16;

    {
        int a = tid >> 4, f0 = (tid & 15) * 8;
        const float* src = emb + (size_t)Z[row0 + a] * 128 + f0;
        float4 v0 = *(const float4*)src;
        float4 v1 = *(const float4*)(src + 4);
        *(float4*)&q[(row0 + a) * 128 + f0] = v0;
        *(float4*)&q[(row0 + a) * 128 + f0 + 4] = v1;
    }
    const int zr = Z[row0 + ar];
    f32x4 a1[2] = {};
    for (int ks = 0; ks < 128; ks += 32) {
        int k = ks + kg * 8;
        half8 af = f32x8_to_h8(emb + (size_t)zr * 128 + k);
#pragma unroll
        for (int tt = 0; tt < 2; ++tt) {
            int t = wave * 2 + tt;
            half8 bf = *(const half8*)&W1t[(size_t)(t * 16 + ar) * 128 + k];
            a1[tt] = __builtin_amdgcn_mfma_f32_16x16x32_f16(af, bf, a1[tt], 0, 0, 0);
        }
    }
#pragma unroll
    for (int tt = 0; tt < 2; ++tt) {
        int col = (wave * 2 + tt) * 16 + ar;
        float bb = b1[col];
#pragma unroll
        for (int r = 0; r < 4; ++r)
            Hs[(kg * 4 + r) * 136 + col] = (h16)silu(a1[tt][r] + bb);
    }
    __syncthreads();
    f32x4 a2[6] = {};
    for (int ks = 0; ks < 128; ks += 32) {
        int k = ks + kg * 8;
        half8 af = *(const half8*)&Hs[ar * 136 + k];
#pragma unroll
        for (int tt = 0; tt < 6; ++tt) {
            int t = wave * 6 + tt;
            half8 bf = *(const half8*)&W2t[(size_t)(t * 16 + ar) * 128 + k];
            a2[tt] = __builtin_amdgcn_mfma_f32_16x16x32_f16(af, bf, a2[tt], 0, 0, 0);
        }
    }
#pragma unroll
    for (int tt = 0; tt < 6; ++tt) {
        int col = (wave * 6 + tt) * 16 + ar;
        float bb = b2[col];
        int slot = col >> 7, ff = col & 127;
#pragma unroll
        for (int r = 0; r < 4; ++r)
            XMP[((kg * 4 + r) * 128 + ff) * 6 + slot] = (h16)(a2[tt][r] + bb);
    }
    __syncthreads();
    {
        const uint4* src = (const uint4*)XMP;
        uint4* dst = (uint4*)(xm + row0 * 768);
#pragma unroll
        for (int i = 0; i < 6; ++i)
            dst[tid + i * 256] = src[tid + i * 256];
    }
}

// ====== edge kernel: persistent blocks, dynamic atom grabbing ======
// Round-2 inner loop verbatim (best measured: 75.7us, absmax 0.25) on the
// merged 64B ed row. Structure change vs round 2: grid=4096 persistent
// blocks, first atom = blockIdx.x, then atomicAdd-grab. Targets the
// measured occupancy ceiling (60%) and tail imbalance; filter regs load
// once per block instead of once per atom.
template<bool HAS_MU>
__global__ __launch_bounds__(128, 8) void edge_kernel(
    const h16* __restrict__ ed, const h16* __restrict__ fwt,
    const int* __restrict__ row_start, const int* __restrict__ idx_j,
    const h16* __restrict__ xm, const float* __restrict__ mup,
    float* __restrict__ mun, h16* __restrict__ mu16n, float* __restrict__ q,
    int* __restrict__ ctr)
{
    const int f = threadIdx.x;
    __shared__ int s_n;
    half8 FA[3], FB[3], FC[3];
    {
        const half8* pa = (const half8*)(fwt + (size_t)f * 32);
        const half8* pb = (const half8*)(fwt + (size_t)(128 + f) * 32);
#pragma unroll
        for (int r = 0; r < 3; ++r) { FA[r] = pa[r]; FB[r] = pb[r]; }
        if (HAS_MU) {
            const half8* pc = (const half8*)(fwt + (size_t)(256 + f) * 32);
#pragma unroll
            for (int r = 0; r < 3; ++r) FC[r] = pc[r];
        }
    }
    asm volatile("" : "+v"(FA[0]), "+v"(FA[1]), "+v"(FA[2]),
                      "+v"(FB[0]), "+v"(FB[1]), "+v"(FB[2]));
    if (HAS_MU)
        asm volatile("" : "+v"(FC[0]), "+v"(FC[1]), "+v"(FC[2]));

    half2v fa[12], fb[12], fc[12];
    *(half8*)&fa[0] = FA[0]; *(half8*)&fa[4] = FA[1]; *(half8*)&fa[8] = FA[2];
    *(half8*)&fb[0] = FB[0]; *(half8*)&fb[4] = FB[1]; *(half8*)&fb[8] = FB[2];
    if (HAS_MU) {
        *(half8*)&fc[0] = FC[0]; *(half8*)&fc[4] = FC[1]; *(half8*)&fc[8] = FC[2];
    }

    const h16* xmf = xm + (size_t)f * 6;
    int n = blockIdx.x;
    while (n < NA) {
        float accq = 0.f, am0 = 0.f, am1 = 0.f, am2 = 0.f;
        const int e0 = row_start[n], e1 = row_start[n + 1];
        if (e0 < e1) {
            // prologue prefetch for edge e0
            int j = idx_j[e0];
            const unsigned* gp = (const unsigned*)(xmf + (size_t)j * 768);
            unsigned g0n = gp[0], g1n = 0u, g2n = 0u;
            if (HAS_MU) { g1n = gp[1]; g2n = gp[2]; }
            const h16* pb8 = ed + (size_t)e0 * 32;
            half8 p0n = *(const half8*)pb8;
            half8 p1n = *(const half8*)(pb8 + 8);
            half8 p2n = *(const half8*)(pb8 + 16);
            float4 dn = *(const float4*)(pb8 + 24);
            for (int e = e0; e < e1; ++e) {
                unsigned g0 = g0n, g1 = g1n, g2 = g2n;
                half8 p0 = p0n, p1 = p1n, p2 = p2n;
                float4 g = dn;
                // prefetch e+1 (clamped: last iteration redundantly re-fetches e)
                int ep = (e + 1 < e1) ? e + 1 : e;
                int j2 = idx_j[ep];
                const unsigned* gp2 = (const unsigned*)(xmf + (size_t)j2 * 768);
                g0n = gp2[0];
                if (HAS_MU) { g1n = gp2[1]; g2n = gp2[2]; }
                const h16* pb2 = ed + (size_t)ep * 32;
                p0n = *(const half8*)pb2;
                p1n = *(const half8*)(pb2 + 8);
                p2n = *(const half8*)(pb2 + 16);
                dn = *(const float4*)(pb2 + 24);
                // ---- compute on current edge ----
                half2v pr[12];
                *(half8*)&pr[0] = p0; *(half8*)&pr[4] = p1; *(half8*)&pr[8] = p2;
                half2v A0 = {(h16)0.f, (h16)0.f}, A1 = A0, A2 = A0;
#pragma unroll
                for (int r = 0; r < 11; ++r) {
                    A0 = pr[r] * fa[r] + A0;
                    A1 = pr[r] * fb[r] + A1;
                    if (HAS_MU) A2 = pr[r] * fc[r] + A2;
                }
                float w0 = (float)A0[0] + (float)A0[1];
                float w1 = (float)A1[0] + (float)A1[1];
                half2v h01 = __builtin_bit_cast(half2v, g0);
                half2v h23 = __builtin_bit_cast(half2v, g1);
                float x0 = (float)h01[0], x1 = (float)h01[1];
                accq = fmaf(w0, x0, accq);
                float xw1 = w1 * x1;
                if (HAS_MU) {
                    float w2 = (float)A2[0] + (float)A2[1];
                    half2v h45 = __builtin_bit_cast(half2v, g2);
                    float x2 = (float)h23[0];
                    float xw2 = w2 * x2;
                    am0 += xw1 * g.x + xw2 * (float)h23[1];
                    am1 += xw1 * g.y + xw2 * (float)h45[0];
                    am2 += xw1 * g.z + xw2 * (float)h45[1];
                } else {
                    am0 = fmaf(xw1, g.x, am0);
                    am1 = fmaf(xw1, g.y, am1);
                    am2 = fmaf(xw1, g.z, am2);
                }
            }
        }
        q[(size_t)n * FD + f] += accq;
        size_t b = (size_t)n * 384;
        float m0 = (HAS_MU ? mup[b + f] : 0.f) + am0;
        float m1 = (HAS_MU ? mup[b + 128 + f] : 0.f) + am1;
        float m2 = (HAS_MU ? mup[b + 256 + f] : 0.f) + am2;
        mun[b + f] = m0; mun[b + 128 + f] = m1; mun[b + 256 + f] = m2;
        mu16n[b + f] = (h16)m0; mu16n[b + 128 + f] = (h16)m1; mu16n[b + 256 + f] = (h16)m2;
        // grab next atom
        __syncthreads();
        if (f == 0) s_n = atomicAdd(ctr, 1);
        __syncthreads();
        n = s_n;
    }
}

// ====== fused mixing (+ optional next-iteration interaction MLP) ======
__global__ __launch_bounds__(256) void mixint_kernel(
    const h16* __restrict__ mu16n, const h16* __restrict__ WmuT,
    const h16* __restrict__ W1t, const float* __restrict__ b1,
    const h16* __restrict__ W2t, const float* __restrict__ b2,
    float* __restrict__ q, float* __restrict__ mu, h16* __restrict__ xmw,
    const h16* __restrict__ nW1t, const float* __restrict__ nb1,
    const h16* __restrict__ nW2t, const float* __restrict__ nb2)
{
    __shared__ __align__(16) h16 MM[48 * 264];   // reused as XMP in nW branch
    __shared__ h16 CT[16 * 264];
    __shared__ h16 Hs[16 * 136];
    __shared__ h16 XM[16 * 392];
    const int tid = threadIdx.x;
    const int wave = tid >> 6, lane = tid & 63;
    const int ar = lane & 15, kg = lane >> 4;
    const size_t row0 = (size_t)blockIdx.x * 16;

    {
        f32x4 acc[3][4] = {};
        int aloc[3], dloc[3];
#pragma unroll
        for (int rt = 0; rt < 3; ++rt) {
            int rr = rt * 16 + ar;
            aloc[rt] = rr / 3;
            dloc[rt] = rr - 3 * aloc[rt];
        }
        for (int ks = 0; ks < 128; ks += 32) {
            int k = ks + kg * 8;
            half8 afr[3];
#pragma unroll
            for (int rt = 0; rt < 3; ++rt)
                afr[rt] = *(const half8*)&mu16n[(row0 + aloc[rt]) * 384 + dloc[rt] * 128 + k];
#pragma unroll
            for (int ct = 0; ct < 4; ++ct) {
                int cc = wave * 4 + ct;
                half8 bf = *(const half8*)&WmuT[(size_t)(cc * 16 + ar) * 128 + k];
#pragma unroll
                for (int rt = 0; rt < 3; ++rt)
                    acc[rt][ct] = __builtin_amdgcn_mfma_f32_16x16x32_f16(afr[rt], bf, acc[rt][ct], 0, 0, 0);
            }
        }
#pragma unroll
        for (int rt = 0; rt < 3; ++rt)
#pragma unroll
            for (int ct = 0; ct < 4; ++ct) {
                int col = (wave * 4 + ct) * 16 + ar;
#pragma unroll
                for (int r = 0; r < 4; ++r)
                    MM[(rt * 16 + kg * 4 + r) * 264 + col] = (h16)acc[rt][ct][r];
            }
    }
    __syncthreads();

    {
        int a = tid >> 4, fi = (tid & 15) * 8;
        const float* qp = q + (row0 + a) * 128 + fi;
        float4 q0 = *(const float4*)qp;
        float4 q1 = *(const float4*)(qp + 4);
        float qv[8] = {q0.x, q0.y, q0.z, q0.w, q1.x, q1.y, q1.z, q1.w};
#pragma unroll
        for (int jj = 0; jj < 8; ++jj) {
            int ff = fi + jj;
            float v0 = (float)MM[(a * 3 + 0) * 264 + ff];
            float v1 = (float)MM[(a * 3 + 1) * 264 + ff];
            float v2 = (float)MM[(a * 3 + 2) * 264 + ff];
            CT[a * 264 + 128 + ff] = (h16)sqrtf(v0 * v0 + v1 * v1 + v2 * v2 + 1e-8f);
            CT[a * 264 + ff] = (h16)qv[jj];
        }
    }
    __syncthreads();

    {
        f32x4 a1[2] = {};
        for (int ks = 0; ks < 256; ks += 32) {
            int k = ks + kg * 8;
            half8 af = *(const half8*)&CT[ar * 264 + k];
#pragma unroll
            for (int tt = 0; tt < 2; ++tt) {
                int t = wave * 2 + tt;
                half8 bf = *(const half8*)&W1t[(size_t)(t * 16 + ar) * 256 + k];
                a1[tt] = __builtin_amdgcn_mfma_f32_16x16x32_f16(af, bf, a1[tt], 0, 0, 0);
            }
        }
#pragma unroll
        for (int tt = 0; tt < 2; ++tt) {
            int col = (wave * 2 + tt) * 16 + ar;
            float bb = b1[col];
#pragma unroll
            for (int r = 0; r < 4; ++r)
                Hs[(kg * 4 + r) * 136 + col] = (h16)silu(a1[tt][r] + bb);
        }
    }
    __syncthreads();

    {
        f32x4 a2[6] = {};
        for (int ks = 0; ks < 128; ks += 32) {
            int k = ks + kg * 8;
            half8 af = *(const half8*)&Hs[ar * 136 + k];
#pragma unroll
            for (int tt = 0; tt < 6; ++tt) {
                int t = wave * 6 + tt;
                half8 bf = *(const half8*)&W2t[(size_t)(t * 16 + ar) * 128 + k];
                a2[tt] = __builtin_amdgcn_mfma_f32_16x16x32_f16(af, bf, a2[tt], 0, 0, 0);
            }
        }
#pragma unroll
        for (int tt = 0; tt < 6; ++tt) {
            int col = (wave * 6 + tt) * 16 + ar;
            float bb = b2[col];
#pragma unroll
            for (int r = 0; r < 4; ++r)
                XM[(kg * 4 + r) * 392 + col] = (h16)(a2[tt][r] + bb);
        }
    }
    __syncthreads();

    h16 mh[24];   // per-thread staged mu16, flushed in nW branch
    {
        int a = tid >> 4, fi = (tid & 15) * 8;
        size_t n = row0 + a;
#pragma unroll
        for (int jj = 0; jj < 8; ++jj) {
            int ff = fi + jj;
            float dq  = (float)XM[a * 392 + ff];
            float dm  = (float)XM[a * 392 + 128 + ff];
            float dqm = (float)XM[a * 392 + 256 + ff];
            float v0 = (float)MM[(a * 3 + 0) * 264 + ff], w0 = (float)MM[(a * 3 + 0) * 264 + 128 + ff];
            float v1 = (float)MM[(a * 3 + 1) * 264 + ff], w1 = (float)MM[(a * 3 + 1) * 264 + 128 + ff];
            float v2 = (float)MM[(a * 3 + 2) * 264 + ff], w2 = (float)MM[(a * 3 + 2) * 264 + 128 + ff];
            float sv = v0 * w0 + v1 * w1 + v2 * w2;
            float qn = q[n * 128 + ff] + dq + dqm * sv;
            q[n * 128 + ff] = qn;
            CT[a * 264 + ff] = (h16)qn;
            size_t b = n * 384 + ff;
            float m0 = mu[b] + dm * w0;
            float m1 = mu[b + 128] + dm * w1;
            float m2 = mu[b + 256] + dm * w2;
            mu[b] = m0; mu[b + 128] = m1; mu[b + 256] = m2;
            mh[jj * 3 + 0] = (h16)m0; mh[jj * 3 + 1] = (h16)m1; mh[jj * 3 + 2] = (h16)m2;
        }
    }
    if (!nW1t) return;
    __syncthreads();

    {
        f32x4 a1[2] = {};
        for (int ks = 0; ks < 128; ks += 32) {
            int k = ks + kg * 8;
            half8 af = *(const half8*)&CT[ar * 264 + k];
#pragma unroll
            for (int tt = 0; tt < 2; ++tt) {
                int t = wave * 2 + tt;
                half8 bf = *(const half8*)&nW1t[(size_t)(t * 16 + ar) * 128 + k];
                a1[tt] = __builtin_amdgcn_mfma_f32_16x16x32_f16(af, bf, a1[tt], 0, 0, 0);
            }
        }
#pragma unroll
        for (int tt = 0; tt < 2; ++tt) {
            int col = (wave * 2 + tt) * 16 + ar;
            float bb = nb1[col];
#pragma unroll
            for (int r = 0; r < 4; ++r)
                Hs[(kg * 4 + r) * 136 + col] = (h16)silu(a1[tt][r] + bb);
        }
        __syncthreads();
        f32x4 a2[6] = {};
        for (int ks = 0; ks < 128; ks += 32) {
            int k = ks + kg * 8;
            half8 af = *(const half8*)&Hs[ar * 136 + k];
#pragma unroll
            for (int tt = 0; tt < 6; ++tt) {
                int t = wave * 6 + tt;
                half8 bf = *(const half8*)&nW2t[(size_t)(t * 16 + ar) * 128 + k];
                a2[tt] = __builtin_amdgcn_mfma_f32_16x16x32_f16(af, bf, a2[tt], 0, 0, 0);
            }
        }
        h16* XMP = MM;
#pragma unroll
        for (int tt = 0; tt < 6; ++tt) {
            int col = (wave * 6 + tt) * 16 + ar;
            float bb = nb2[col];
            int slot = col >> 7, ff = col & 127;
#pragma unroll
            for (int r = 0; r < 4; ++r)
                XMP[((kg * 4 + r) * 128 + ff) * 6 + slot] = (h16)(a2[tt][r] + bb);
        }
        {
            int a = tid >> 4, fi = (tid & 15) * 8;
#pragma unroll
            for (int jj = 0; jj < 8; ++jj)
#pragma unroll
                for (int s = 0; s < 3; ++s)
                    XMP[(a * 128 + fi + jj) * 6 + 3 + s] = mh[jj * 3 + s];
        }
        __syncthreads();
        {
            const uint4* src = (const uint4*)MM;
            uint4* dst = (uint4*)(xmw + row0 * 768);
#pragma unroll
            for (int i = 0; i < 6; ++i)
                dst[tid + i * 256] = src[tid + i * 256];
        }
    }
}

// ====== launch ======
extern "C" void kernel_launch(void* const* d_in, const int* in_sizes, int n_in,
                              void* d_out, int out_size, void* d_ws, size_t ws_size,
                              hipStream_t stream)
{
    const int*   Z       = (const int*)d_in[0];
    const float* R       = (const float*)d_in[1];
    const int*   idx_i   = (const int*)d_in[2];
    const int*   idx_j   = (const int*)d_in[3];
    const float* offsets = (const float*)d_in[4];
    const float* emb     = (const float*)d_in[5];
    const float* filt_W  = (const float*)d_in[6];
    const float* filt_b  = (const float*)d_in[7];
    const float* int_W1  = (const float*)d_in[8];
    const float* int_b1  = (const float*)d_in[9];
    const float* int_W2  = (const float*)d_in[10];
    const float* int_b2  = (const float*)d_in[11];
    const float* mix_Wmu = (const float*)d_in[12];
    const float* mix_W1  = (const float*)d_in[13];
    const float* mix_b1  = (const float*)d_in[14];
    const float* mix_W2  = (const float*)d_in[15];
    const float* mix_b2  = (const float*)d_in[16];

    float* q_out  = (float*)d_out;
    float* mu_out = (float*)d_out + (size_t)NA * FD;

    char* base = (char*)d_ws;
    size_t o = 0;
    auto alloc = [&](size_t bytes) -> void* {
        void* p = base + o;
        o += (bytes + 255) & ~(size_t)255;
        return p;
    };
    h16*   ed     = (h16*)alloc((size_t)NE * 32 * 2);        // merged ph+dir, 64B/edge
    h16*   xm     = (h16*)alloc((size_t)NA * 128 * 6 * 2);   // packed x+mu for edge gather
    h16*   mu16p  = (h16*)alloc((size_t)NA * 384 * 2);       // planar pre-mix mu
    float* mu_ws  = (float*)alloc((size_t)NA * 384 * 4);
    h16*   W1t    = (h16*)alloc((size_t)3 * 128 * 128 * 2);
    h16*   W2t    = (h16*)alloc((size_t)3 * 384 * 128 * 2);
    h16*   WmuT   = (h16*)alloc((size_t)3 * 256 * 128 * 2);
    h16*   mW1t   = (h16*)alloc((size_t)3 * 128 * 256 * 2);
    h16*   mW2t   = (h16*)alloc((size_t)3 * 384 * 128 * 2);
    h16*   fwt    = (h16*)alloc((size_t)384 * 32 * 2);
    int*   row_st = (int*)alloc((size_t)(NA + 1) * 4);
    int*   ctr    = (int*)alloc((size_t)4 * 4);

    setup_kernel<<<3177, 256, 0, stream>>>(R, idx_i, idx_j, offsets, ed, row_st,
                                           int_W1, int_W2, mix_Wmu, mix_W1, mix_W2,
                                           W1t, W2t, WmuT, mW1t, mW2t,
                                           filt_W, filt_b, fwt, ctr);

    // iteration 0
    intmlp0_kernel<<<NA / 16, 256, 0, stream>>>(Z, emb, q_out,
                                                W1t, int_b1, W2t, int_b2, xm);
    edge_kernel<false><<<EDGE_GRID, 128, 0, stream>>>(ed, fwt, row_st, idx_j,
                                                      xm, nullptr, mu_out, mu16p, q_out, ctr + 0);
    mixint_kernel<<<NA / 16, 256, 0, stream>>>(
        mu16p, WmuT, mW1t, mix_b1, mW2t, mix_b2, q_out, mu_out, xm,
        W1t + 16384, int_b1 + 128, W2t + 49152, int_b2 + 384);

    // iteration 1
    edge_kernel<true><<<EDGE_GRID, 128, 0, stream>>>(ed, fwt, row_st, idx_j,
                                                     xm, mu_out, mu_ws, mu16p, q_out, ctr + 1);
    mixint_kernel<<<NA / 16, 256, 0, stream>>>(
        mu16p, WmuT + 32768, mW1t + 32768, mix_b1 + 128, mW2t + 49152, mix_b2 + 384,
        q_out, mu_ws, xm,
        W1t + 32768, int_b1 + 256, W2t + 98304, int_b2 + 768);

    // iteration 2
    edge_kernel<true><<<EDGE_GRID, 128, 0, stream>>>(ed, fwt, row_st, idx_j,
                                                     xm, mu_ws, mu_out, mu16p, q_out, ctr + 2);
    mixint_kernel<<<NA / 16, 256, 0, stream>>>(
        mu16p, WmuT + 65536, mW1t + 65536, mix_b1 + 256, mW2t + 98304, mix_b2 + 768,
        q_out, mu_out, xm,
        nullptr, nullptr, nullptr, nullptr);
}

// Round 5
// 446.619 us; speedup vs baseline: 1.4466x; 1.4466x over previous
//
#include <hip/hip_runtime.h>
#include <math.h>

#define NA 10000
#define NE 250000
#define FD 128
#define NRBF 20
#define RCUT 5.0f
#define NB 8            // j-buckets per atom
#define BDIV 1250       // NA / NB

typedef _Float16 h16;
typedef __attribute__((ext_vector_type(8))) _Float16 half8;
typedef __attribute__((ext_vector_type(2))) _Float16 half2v;
typedef __attribute__((ext_vector_type(4))) float f32x4;

static __device__ __forceinline__ half8 f32x8_to_h8(const float* p) {
    float4 a = *(const float4*)p;
    float4 b = *(const float4*)(p + 4);
    half8 r;
    r[0] = (h16)a.x; r[1] = (h16)a.y; r[2] = (h16)a.z; r[3] = (h16)a.w;
    r[4] = (h16)b.x; r[5] = (h16)b.y; r[6] = (h16)b.z; r[7] = (h16)b.w;
    return r;
}
static __device__ __forceinline__ float silu(float v) {
    return v / (1.f + expf(-v));
}

// ====== K1: per-(atom,bucket) edge counts + CSR row_start ======
__global__ __launch_bounds__(256) void count_kernel(
    const int* __restrict__ idx_i, const int* __restrict__ idx_j,
    int* __restrict__ cnt, int* __restrict__ row_start)
{
    const int b = blockIdx.x;
    if (b < 977) {
        int e = b * 256 + threadIdx.x;
        if (e >= NE) return;
        int i = idx_i[e];
        int p = idx_j[e] / BDIV;
        atomicAdd(&cnt[i * NB + p], 1);
    } else {
        int n = (b - 977) * 256 + threadIdx.x;
        if (n > NA) return;
        int lo = 0, hi = NE;
        while (lo < hi) {
            int mid = (lo + hi) >> 1;
            if (idx_i[mid] < n) lo = mid + 1; else hi = mid;
        }
        row_start[n] = lo;
    }
}

// ====== K2: per-atom prefix over buckets -> boff (starts) and cur ======
__global__ __launch_bounds__(256) void prefix_kernel(
    const int* __restrict__ row_start, const int* __restrict__ cnt,
    int* __restrict__ boff, int* __restrict__ cur)
{
    int n = blockIdx.x * 256 + threadIdx.x;
    if (n == 0) boff[NA * NB] = NE;
    if (n >= NA) return;
    int s = row_start[n];
#pragma unroll
    for (int p = 0; p < NB; ++p) {
        boff[n * NB + p] = s;
        cur[n * NB + p] = s;
        s += cnt[n * NB + p];
    }
}

// ====== K3: geometry (scatter-written in bucketed order) | weights ======
// ed[np] = one 64B row: 24 h16 (20 gauss*fcut, fcut, 3 zero) + float4 dir.
__global__ __launch_bounds__(256) void setup_kernel(
    const float* __restrict__ R, const int* __restrict__ idx_i,
    const int* __restrict__ idx_j, const float* __restrict__ offsets,
    h16* __restrict__ ed, int* __restrict__ ej, int* __restrict__ cur,
    const float* __restrict__ int_W1, const float* __restrict__ int_W2,
    const float* __restrict__ mix_Wmu, const float* __restrict__ mix_W1,
    const float* __restrict__ mix_W2,
    h16* __restrict__ W1t, h16* __restrict__ W2t, h16* __restrict__ WmuT,
    h16* __restrict__ mW1t, h16* __restrict__ mW2t,
    const float* __restrict__ filt_W, const float* __restrict__ filt_b,
    h16* __restrict__ fwt)
{
    const int b = blockIdx.x;
    if (b < 977) {
        int e = b * 256 + threadIdx.x;
        if (e >= NE) return;
        int i = idx_i[e], j = idx_j[e];
        float rx = R[j * 3 + 0] - R[i * 3 + 0] + offsets[e * 3 + 0];
        float ry = R[j * 3 + 1] - R[i * 3 + 1] + offsets[e * 3 + 1];
        float rz = R[j * 3 + 2] - R[i * 3 + 2] + offsets[e * 3 + 2];
        float d = sqrtf(rx * rx + ry * ry + rz * rz);
        float inv = 1.f / d;
        float fcut = 0.f;
        if (d < RCUT) fcut = 0.5f * (cosf(d * (3.14159265358979323846f / RCUT)) + 1.f);
        int p = j / BDIV;
        int np = atomicAdd(&cur[i * NB + p], 1);
        h16* pp = ed + (size_t)np * 32;
        const float delta = RCUT / 19.f;
        const float coeff = -0.5f / (delta * delta);
#pragma unroll
        for (int r = 0; r < NRBF; ++r) {
            float dc = d - (float)r * delta;
            pp[r] = (h16)(expf(coeff * dc * dc) * fcut);
        }
        pp[20] = (h16)fcut;
        pp[21] = (h16)0.f; pp[22] = (h16)0.f; pp[23] = (h16)0.f;
        *(float4*)(pp + 24) = make_float4(rx * inv, ry * inv, rz * inv, 0.f);
        ej[np] = j;
    } else {
        int idx = (b - 977) * 256 + threadIdx.x;
        if (idx < 49152) {                       // int_W1: K=128,N=128
            int bt = idx >> 14, rem = idx & 16383;
            int nn = rem >> 7, kk = rem & 127;
            W1t[idx] = (h16)int_W1[(size_t)bt * 16384 + kk * 128 + nn];
        } else if ((idx -= 49152) < 147456) {    // int_W2: K=128,N=384
            int bt = idx / 49152, rem = idx - bt * 49152;
            int nn = rem >> 7, kk = rem & 127;
            W2t[idx] = (h16)int_W2[(size_t)bt * 49152 + kk * 384 + nn];
        } else if ((idx -= 147456) < 98304) {    // mix_Wmu: K=128,N=256
            int bt = idx >> 15, rem = idx & 32767;
            int nn = rem >> 7, kk = rem & 127;
            WmuT[idx] = (h16)mix_Wmu[(size_t)bt * 32768 + kk * 256 + nn];
        } else if ((idx -= 98304) < 98304) {     // mix_W1: K=256,N=128
            int bt = idx >> 15, rem = idx & 32767;
            int nn = rem >> 8, kk = rem & 255;
            mW1t[idx] = (h16)mix_W1[(size_t)bt * 32768 + kk * 128 + nn];
        } else if ((idx -= 98304) < 147456) {    // mix_W2: K=128,N=384
            int bt = idx / 49152, rem = idx - bt * 49152;
            int nn = rem >> 7, kk = rem & 127;
            mW2t[idx] = (h16)mix_W2[(size_t)bt * 49152 + kk * 384 + nn];
        } else if ((idx -= 147456) < 12288) {    // fwt [384][32]
            int nn = idx >> 5, kk = idx & 31;
            float v = 0.f;
            if (kk < 20) v = filt_W[kk * 384 + nn];
            else if (kk == 20) v = filt_b[nn];
            fwt[idx] = (h16)v;
        }
    }
}

// ====== iteration-0 interaction MLP: q = emb[Z]; x = silu(q@W1+b1)@W2+b2 ==
// Writes COMPACT x01c[atom][128][2] = (x0,x1) only — iter-0 edge<false>
// never uses x2 (mu=0), and 4B/lane gather = 100% line utilization.
__global__ __launch_bounds__(256) void intmlp0_kernel(
    const int* __restrict__ Z, const float* __restrict__ emb, float* __restrict__ q,
    const h16* __restrict__ W1t, const float* __restrict__ b1,
    const h16* __restrict__ W2t, const float* __restrict__ b2, h16* __restrict__ x01c)
{
    __shared__ h16 Hs[16 * 136];
    const int tid = threadIdx.x;
    const int wave = tid >> 6, lane = tid & 63;
    const int ar = lane & 15, kg = lane >> 4;
    const size_t row0 = (size_t)blockIdx.x * 16;

    {
        int a = tid >> 4, f0 = (tid & 15) * 8;
        const float* src = emb + (size_t)Z[row0 + a] * 128 + f0;
        float4 v0 = *(const float4*)src;
        float4 v1 = *(const float4*)(src + 4);
        *(float4*)&q[(row0 + a) * 128 + f0] = v0;
        *(float4*)&q[(row0 + a) * 128 + f0 + 4] = v1;
    }
    const int zr = Z[row0 + ar];
    f32x4 a1[2] = {};
    for (int ks = 0; ks < 128; ks += 32) {
        int k = ks + kg * 8;
        half8 af = f32x8_to_h8(emb + (size_t)zr * 128 + k);
#pragma unroll
        for (int tt = 0; tt < 2; ++tt) {
            int t = wave * 2 + tt;
            half8 bf = *(const half8*)&W1t[(size_t)(t * 16 + ar) * 128 + k];
            a1[tt] = __builtin_amdgcn_mfma_f32_16x16x32_f16(af, bf, a1[tt], 0, 0, 0);
        }
    }
#pragma unroll
    for (int tt = 0; tt < 2; ++tt) {
        int col = (wave * 2 + tt) * 16 + ar;
        float bb = b1[col];
#pragma unroll
        for (int r = 0; r < 4; ++r)
            Hs[(kg * 4 + r) * 136 + col] = (h16)silu(a1[tt][r] + bb);
    }
    __syncthreads();
    f32x4 a2[6] = {};
    for (int ks = 0; ks < 128; ks += 32) {
        int k = ks + kg * 8;
        half8 af = *(const half8*)&Hs[ar * 136 + k];
#pragma unroll
        for (int tt = 0; tt < 6; ++tt) {
            int t = wave * 6 + tt;
            half8 bf = *(const half8*)&W2t[(size_t)(t * 16 + ar) * 128 + k];
            a2[tt] = __builtin_amdgcn_mfma_f32_16x16x32_f16(af, bf, a2[tt], 0, 0, 0);
        }
    }
#pragma unroll
    for (int tt = 0; tt < 6; ++tt) {
        int col = (wave * 6 + tt) * 16 + ar;
        if (col < 256) {                         // x2 (col>=256) unused at iter 0
            float bb = b2[col];
            int slot = col >> 7, ff = col & 127;
#pragma unroll
            for (int r = 0; r < 4; ++r)
                x01c[((row0 + kg * 4 + r) * 128 + ff) * 2 + slot] = (h16)(a2[tt][r] + bb);
        }
    }
}

// ====== edge kernel: round-2 body verbatim, j-bucketed sweep ======
// Accumulators live in registers across the 8 bucket passes; at any instant
// co-resident blocks gather from a ~1.9MB slice of the x/mu table (fits the
// 4MB per-XCD L2; the unbucketed 15.4MB working set was the 142MB FETCH
// over-fetch). gat = x01c (4B/lane rows) for !HAS_MU, xm (12B/lane) for MU.
template<bool HAS_MU>
__global__ __launch_bounds__(128, 4) void edge_kernel(
    const h16* __restrict__ ed, const h16* __restrict__ fwt,
    const int* __restrict__ boff, const int* __restrict__ ej,
    const h16* __restrict__ gat, const float* __restrict__ mup,
    float* __restrict__ mun, h16* __restrict__ mu16n, float* __restrict__ q)
{
    const int n = blockIdx.x, f = threadIdx.x;
    half8 FA[3], FB[3], FC[3];
    {
        const half8* pa = (const half8*)(fwt + (size_t)f * 32);
        const half8* pb = (const half8*)(fwt + (size_t)(128 + f) * 32);
#pragma unroll
        for (int r = 0; r < 3; ++r) { FA[r] = pa[r]; FB[r] = pb[r]; }
        if (HAS_MU) {
            const half8* pc = (const half8*)(fwt + (size_t)(256 + f) * 32);
#pragma unroll
            for (int r = 0; r < 3; ++r) FC[r] = pc[r];
        }
    }
    asm volatile("" : "+v"(FA[0]), "+v"(FA[1]), "+v"(FA[2]),
                      "+v"(FB[0]), "+v"(FB[1]), "+v"(FB[2]));
    if (HAS_MU)
        asm volatile("" : "+v"(FC[0]), "+v"(FC[1]), "+v"(FC[2]));

    half2v fa[12], fb[12], fc[12];
    *(half8*)&fa[0] = FA[0]; *(half8*)&fa[4] = FA[1]; *(half8*)&fa[8] = FA[2];
    *(half8*)&fb[0] = FB[0]; *(half8*)&fb[4] = FB[1]; *(half8*)&fb[8] = FB[2];
    if (HAS_MU) {
        *(half8*)&fc[0] = FC[0]; *(half8*)&fc[4] = FC[1]; *(half8*)&fc[8] = FC[2];
    }

    const size_t rstr = HAS_MU ? 768 : 256;      // h16 units per gather row
    const h16* xmf = gat + (HAS_MU ? (size_t)f * 6 : (size_t)f * 2);
    float accq = 0.f, am0 = 0.f, am1 = 0.f, am2 = 0.f;

    const int nb8 = n * NB;
    int ebeg = boff[nb8];
    for (int p = 0; p < NB; ++p) {
        const int e0 = ebeg, e1 = boff[nb8 + p + 1];
        ebeg = e1;
        if (e0 >= e1) continue;
        // prologue prefetch for edge e0
        int j = ej[e0];
        const unsigned* gp = (const unsigned*)(xmf + (size_t)j * rstr);
        unsigned g0n = gp[0], g1n = 0u, g2n = 0u;
        if (HAS_MU) { g1n = gp[1]; g2n = gp[2]; }
        const h16* pb8 = ed + (size_t)e0 * 32;
        half8 p0n = *(const half8*)pb8;
        half8 p1n = *(const half8*)(pb8 + 8);
        half8 p2n = *(const half8*)(pb8 + 16);
        float4 dn = *(const float4*)(pb8 + 24);
        for (int e = e0; e < e1; ++e) {
            unsigned g0 = g0n, g1 = g1n, g2 = g2n;
            half8 p0 = p0n, p1 = p1n, p2 = p2n;
            float4 g = dn;
            // prefetch e+1 (clamped: last iteration redundantly re-fetches e)
            int ep = (e + 1 < e1) ? e + 1 : e;
            int j2 = ej[ep];
            const unsigned* gp2 = (const unsigned*)(xmf + (size_t)j2 * rstr);
            g0n = gp2[0];
            if (HAS_MU) { g1n = gp2[1]; g2n = gp2[2]; }
            const h16* pb2 = ed + (size_t)ep * 32;
            p0n = *(const half8*)pb2;
            p1n = *(const half8*)(pb2 + 8);
            p2n = *(const half8*)(pb2 + 16);
            dn = *(const float4*)(pb2 + 24);
            // ---- compute on current edge (round-2 body, do not touch) ----
            half2v pr[12];
            *(half8*)&pr[0] = p0; *(half8*)&pr[4] = p1; *(half8*)&pr[8] = p2;
            half2v A0 = {(h16)0.f, (h16)0.f}, A1 = A0, A2 = A0;
#pragma unroll
            for (int r = 0; r < 11; ++r) {
                A0 = pr[r] * fa[r] + A0;
                A1 = pr[r] * fb[r] + A1;
                if (HAS_MU) A2 = pr[r] * fc[r] + A2;
            }
            float w0 = (float)A0[0] + (float)A0[1];
            float w1 = (float)A1[0] + (float)A1[1];
            half2v h01 = __builtin_bit_cast(half2v, g0);
            half2v h23 = __builtin_bit_cast(half2v, g1);
            float x0 = (float)h01[0], x1 = (float)h01[1];
            accq = fmaf(w0, x0, accq);
            float xw1 = w1 * x1;
            if (HAS_MU) {
                float w2 = (float)A2[0] + (float)A2[1];
                half2v h45 = __builtin_bit_cast(half2v, g2);
                float x2 = (float)h23[0];
                float xw2 = w2 * x2;
                am0 += xw1 * g.x + xw2 * (float)h23[1];
                am1 += xw1 * g.y + xw2 * (float)h45[0];
                am2 += xw1 * g.z + xw2 * (float)h45[1];
            } else {
                am0 = fmaf(xw1, g.x, am0);
                am1 = fmaf(xw1, g.y, am1);
                am2 = fmaf(xw1, g.z, am2);
            }
        }
    }

    q[(size_t)n * FD + f] += accq;
    size_t b = (size_t)n * 384;
    float m0 = (HAS_MU ? mup[b + f] : 0.f) + am0;
    float m1 = (HAS_MU ? mup[b + 128 + f] : 0.f) + am1;
    float m2 = (HAS_MU ? mup[b + 256 + f] : 0.f) + am2;
    mun[b + f] = m0; mun[b + 128 + f] = m1; mun[b + 256 + f] = m2;
    mu16n[b + f] = (h16)m0; mu16n[b + 128 + f] = (h16)m1; mu16n[b + 256 + f] = (h16)m2;
}

// ====== fused mixing (+ optional next-iteration interaction MLP) ======
__global__ __launch_bounds__(256) void mixint_kernel(
    const h16* __restrict__ mu16n, const h16* __restrict__ WmuT,
    const h16* __restrict__ W1t, const float* __restrict__ b1,
    const h16* __restrict__ W2t, const float* __restrict__ b2,
    float* __restrict__ q, float* __restrict__ mu, h16* __restrict__ xmw,
    const h16* __restrict__ nW1t, const float* __restrict__ nb1,
    const h16* __restrict__ nW2t, const float* __restrict__ nb2)
{
    __shared__ __align__(16) h16 MM[48 * 264];   // reused as XMP in nW branch
    __shared__ h16 CT[16 * 264];
    __shared__ h16 Hs[16 * 136];
    __shared__ h16 XM[16 * 392];
    const int tid = threadIdx.x;
    const int wave = tid >> 6, lane = tid & 63;
    const int ar = lane & 15, kg = lane >> 4;
    const size_t row0 = (size_t)blockIdx.x * 16;

    {
        f32x4 acc[3][4] = {};
        int aloc[3], dloc[3];
#pragma unroll
        for (int rt = 0; rt < 3; ++rt) {
            int rr = rt * 16 + ar;
            aloc[rt] = rr / 3;
            dloc[rt] = rr - 3 * aloc[rt];
        }
        for (int ks = 0; ks < 128; ks += 32) {
            int k = ks + kg * 8;
            half8 afr[3];
#pragma unroll
            for (int rt = 0; rt < 3; ++rt)
                afr[rt] = *(const half8*)&mu16n[(row0 + aloc[rt]) * 384 + dloc[rt] * 128 + k];
#pragma unroll
            for (int ct = 0; ct < 4; ++ct) {
                int cc = wave * 4 + ct;
                half8 bf = *(const half8*)&WmuT[(size_t)(cc * 16 + ar) * 128 + k];
#pragma unroll
                for (int rt = 0; rt < 3; ++rt)
                    acc[rt][ct] = __builtin_amdgcn_mfma_f32_16x16x32_f16(afr[rt], bf, acc[rt][ct], 0, 0, 0);
            }
        }
#pragma unroll
        for (int rt = 0; rt < 3; ++rt)
#pragma unroll
            for (int ct = 0; ct < 4; ++ct) {
                int col = (wave * 4 + ct) * 16 + ar;
#pragma unroll
                for (int r = 0; r < 4; ++r)
                    MM[(rt * 16 + kg * 4 + r) * 264 + col] = (h16)acc[rt][ct][r];
            }
    }
    __syncthreads();

    {
        int a = tid >> 4, fi = (tid & 15) * 8;
        const float* qp = q + (row0 + a) * 128 + fi;
        float4 q0 = *(const float4*)qp;
        float4 q1 = *(const float4*)(qp + 4);
        float qv[8] = {q0.x, q0.y, q0.z, q0.w, q1.x, q1.y, q1.z, q1.w};
#pragma unroll
        for (int jj = 0; jj < 8; ++jj) {
            int ff = fi + jj;
            float v0 = (float)MM[(a * 3 + 0) * 264 + ff];
            float v1 = (float)MM[(a * 3 + 1) * 264 + ff];
            float v2 = (float)MM[(a * 3 + 2) * 264 + ff];
            CT[a * 264 + 128 + ff] = (h16)sqrtf(v0 * v0 + v1 * v1 + v2 * v2 + 1e-8f);
            CT[a * 264 + ff] = (h16)qv[jj];
        }
    }
    __syncthreads();

    {
        f32x4 a1[2] = {};
        for (int ks = 0; ks < 256; ks += 32) {
            int k = ks + kg * 8;
            half8 af = *(const half8*)&CT[ar * 264 + k];
#pragma unroll
            for (int tt = 0; tt < 2; ++tt) {
                int t = wave * 2 + tt;
                half8 bf = *(const half8*)&W1t[(size_t)(t * 16 + ar) * 256 + k];
                a1[tt] = __builtin_amdgcn_mfma_f32_16x16x32_f16(af, bf, a1[tt], 0, 0, 0);
            }
        }
#pragma unroll
        for (int tt = 0; tt < 2; ++tt) {
            int col = (wave * 2 + tt) * 16 + ar;
            float bb = b1[col];
#pragma unroll
            for (int r = 0; r < 4; ++r)
                Hs[(kg * 4 + r) * 136 + col] = (h16)silu(a1[tt][r] + bb);
        }
    }
    __syncthreads();

    {
        f32x4 a2[6] = {};
        for (int ks = 0; ks < 128; ks += 32) {
            int k = ks + kg * 8;
            half8 af = *(const half8*)&Hs[ar * 136 + k];
#pragma unroll
            for (int tt = 0; tt < 6; ++tt) {
                int t = wave * 6 + tt;
                half8 bf = *(const half8*)&W2t[(size_t)(t * 16 + ar) * 128 + k];
                a2[tt] = __builtin_amdgcn_mfma_f32_16x16x32_f16(af, bf, a2[tt], 0, 0, 0);
            }
        }
#pragma unroll
        for (int tt = 0; tt < 6; ++tt) {
            int col = (wave * 6 + tt) * 16 + ar;
            float bb = b2[col];
#pragma unroll
            for (int r = 0; r < 4; ++r)
                XM[(kg * 4 + r) * 392 + col] = (h16)(a2[tt][r] + bb);
        }
    }
    __syncthreads();

    h16 mh[24];   // per-thread staged mu16, flushed in nW branch
    {
        int a = tid >> 4, fi = (tid & 15) * 8;
        size_t n = row0 + a;
#pragma unroll
        for (int jj = 0; jj < 8; ++jj) {
            int ff = fi + jj;
            float dq  = (float)XM[a * 392 + ff];
            float dm  = (float)XM[a * 392 + 128 + ff];
            float dqm = (float)XM[a * 392 + 256 + ff];
            float v0 = (float)MM[(a * 3 + 0) * 264 + ff], w0 = (float)MM[(a * 3 + 0) * 264 + 128 + ff];
            float v1 = (float)MM[(a * 3 + 1) * 264 + ff], w1 = (float)MM[(a * 3 + 1) * 264 + 128 + ff];
            float v2 = (float)MM[(a * 3 + 2) * 264 + ff], w2 = (float)MM[(a * 3 + 2) * 264 + 128 + ff];
            float sv = v0 * w0 + v1 * w1 + v2 * w2;
            float qn = q[n * 128 + ff] + dq + dqm * sv;
            q[n * 128 + ff] = qn;
            CT[a * 264 + ff] = (h16)qn;
            size_t b = n * 384 + ff;
            float m0 = mu[b] + dm * w0;
            float m1 = mu[b + 128] + dm * w1;
            float m2 = mu[b + 256] + dm * w2;
            mu[b] = m0; mu[b + 128] = m1; mu[b + 256] = m2;
            mh[jj * 3 + 0] = (h16)m0; mh[jj * 3 + 1] = (h16)m1; mh[jj * 3 + 2] = (h16)m2;
        }
    }
    if (!nW1t) return;
    __syncthreads();

    {
        f32x4 a1[2] = {};
        for (int ks = 0; ks < 128; ks += 32) {
            int k = ks + kg * 8;
            half8 af = *(const half8*)&CT[ar * 264 + k];
#pragma unroll
            for (int tt = 0; tt < 2; ++tt) {
                int t = wave * 2 + tt;
                half8 bf = *(const half8*)&nW1t[(size_t)(t * 16 + ar) * 128 + k];
                a1[tt] = __builtin_amdgcn_mfma_f32_16x16x32_f16(af, bf, a1[tt], 0, 0, 0);
            }
        }
#pragma unroll
        for (int tt = 0; tt < 2; ++tt) {
            int col = (wave * 2 + tt) * 16 + ar;
            float bb = nb1[col];
#pragma unroll
            for (int r = 0; r < 4; ++r)
                Hs[(kg * 4 + r) * 136 + col] = (h16)silu(a1[tt][r] + bb);
        }
        __syncthreads();
        f32x4 a2[6] = {};
        for (int ks = 0; ks < 128; ks += 32) {
            int k = ks + kg * 8;
            half8 af = *(const half8*)&Hs[ar * 136 + k];
#pragma unroll
            for (int tt = 0; tt < 6; ++tt) {
                int t = wave * 6 + tt;
                half8 bf = *(const half8*)&nW2t[(size_t)(t * 16 + ar) * 128 + k];
                a2[tt] = __builtin_amdgcn_mfma_f32_16x16x32_f16(af, bf, a2[tt], 0, 0, 0);
            }
        }
        h16* XMP = MM;
#pragma unroll
        for (int tt = 0; tt < 6; ++tt) {
            int col = (wave * 6 + tt) * 16 + ar;
            float bb = nb2[col];
            int slot = col >> 7, ff = col & 127;
#pragma unroll
            for (int r = 0; r < 4; ++r)
                XMP[((kg * 4 + r) * 128 + ff) * 6 + slot] = (h16)(a2[tt][r] + bb);
        }
        {
            int a = tid >> 4, fi = (tid & 15) * 8;
#pragma unroll
            for (int jj = 0; jj < 8; ++jj)
#pragma unroll
                for (int s = 0; s < 3; ++s)
                    XMP[(a * 128 + fi + jj) * 6 + 3 + s] = mh[jj * 3 + s];
        }
        __syncthreads();
        {
            const uint4* src = (const uint4*)MM;
            uint4* dst = (uint4*)(xmw + row0 * 768);
#pragma unroll
            for (int i = 0; i < 6; ++i)
                dst[tid + i * 256] = src[tid + i * 256];
        }
    }
}

// ====== launch ======
extern "C" void kernel_launch(void* const* d_in, const int* in_sizes, int n_in,
                              void* d_out, int out_size, void* d_ws, size_t ws_size,
                              hipStream_t stream)
{
    const int*   Z       = (const int*)d_in[0];
    const float* R       = (const float*)d_in[1];
    const int*   idx_i   = (const int*)d_in[2];
    const int*   idx_j   = (const int*)d_in[3];
    const float* offsets = (const float*)d_in[4];
    const float* emb     = (const float*)d_in[5];
    const float* filt_W  = (const float*)d_in[6];
    const float* filt_b  = (const float*)d_in[7];
    const float* int_W1  = (const float*)d_in[8];
    const float* int_b1  = (const float*)d_in[9];
    const float* int_W2  = (const float*)d_in[10];
    const float* int_b2  = (const float*)d_in[11];
    const float* mix_Wmu = (const float*)d_in[12];
    const float* mix_W1  = (const float*)d_in[13];
    const float* mix_b1  = (const float*)d_in[14];
    const float* mix_W2  = (const float*)d_in[15];
    const float* mix_b2  = (const float*)d_in[16];

    float* q_out  = (float*)d_out;
    float* mu_out = (float*)d_out + (size_t)NA * FD;

    char* base = (char*)d_ws;
    size_t o = 0;
    auto alloc = [&](size_t bytes) -> void* {
        void* p = base + o;
        o += (bytes + 255) & ~(size_t)255;
        return p;
    };
    h16*   ed     = (h16*)alloc((size_t)NE * 32 * 2);        // merged ph+dir, 64B/edge (bucketed order)
    int*   ej     = (int*)alloc((size_t)NE * 4);             // idx_j in bucketed order
    h16*   xm     = (h16*)alloc((size_t)NA * 128 * 6 * 2);   // packed x+mu for edge gather
    h16*   x01c   = (h16*)alloc((size_t)NA * 128 * 2 * 2);   // compact (x0,x1) for iter-0 edge
    h16*   mu16p  = (h16*)alloc((size_t)NA * 384 * 2);       // planar pre-mix mu
    float* mu_ws  = (float*)alloc((size_t)NA * 384 * 4);
    h16*   W1t    = (h16*)alloc((size_t)3 * 128 * 128 * 2);
    h16*   W2t    = (h16*)alloc((size_t)3 * 384 * 128 * 2);
    h16*   WmuT   = (h16*)alloc((size_t)3 * 256 * 128 * 2);
    h16*   mW1t   = (h16*)alloc((size_t)3 * 128 * 256 * 2);
    h16*   mW2t   = (h16*)alloc((size_t)3 * 384 * 128 * 2);
    h16*   fwt    = (h16*)alloc((size_t)384 * 32 * 2);
    int*   row_st = (int*)alloc((size_t)(NA + 1) * 4);
    int*   cnt    = (int*)alloc((size_t)NA * NB * 4);
    int*   boff   = (int*)alloc((size_t)(NA * NB + 1) * 4);
    int*   cur    = (int*)alloc((size_t)NA * NB * 4);

    hipMemsetAsync(cnt, 0, (size_t)NA * NB * 4, stream);
    count_kernel<<<1017, 256, 0, stream>>>(idx_i, idx_j, cnt, row_st);
    prefix_kernel<<<40, 256, 0, stream>>>(row_st, cnt, boff, cur);
    setup_kernel<<<3137, 256, 0, stream>>>(R, idx_i, idx_j, offsets, ed, ej, cur,
                                           int_W1, int_W2, mix_Wmu, mix_W1, mix_W2,
                                           W1t, W2t, WmuT, mW1t, mW2t,
                                           filt_W, filt_b, fwt);

    // iteration 0
    intmlp0_kernel<<<NA / 16, 256, 0, stream>>>(Z, emb, q_out,
                                                W1t, int_b1, W2t, int_b2, x01c);
    edge_kernel<false><<<NA, 128, 0, stream>>>(ed, fwt, boff, ej,
                                               x01c, nullptr, mu_out, mu16p, q_out);
    mixint_kernel<<<NA / 16, 256, 0, stream>>>(
        mu16p, WmuT, mW1t, mix_b1, mW2t, mix_b2, q_out, mu_out, xm,
        W1t + 16384, int_b1 + 128, W2t + 49152, int_b2 + 384);

    // iteration 1
    edge_kernel<true><<<NA, 128, 0, stream>>>(ed, fwt, boff, ej,
                                              xm, mu_out, mu_ws, mu16p, q_out);
    mixint_kernel<<<NA / 16, 256, 0, stream>>>(
        mu16p, WmuT + 32768, mW1t + 32768, mix_b1 + 128, mW2t + 49152, mix_b2 + 384,
        q_out, mu_ws, xm,
        W1t + 32768, int_b1 + 256, W2t + 98304, int_b2 + 768);

    // iteration 2
    edge_kernel<true><<<NA, 128, 0, stream>>>(ed, fwt, boff, ej,
                                              xm, mu_ws, mu_out, mu16p, q_out);
    mixint_kernel<<<NA / 16, 256, 0, stream>>>(
        mu16p, WmuT + 65536, mW1t + 65536, mix_b1 + 256, mW2t + 98304, mix_b2 + 768,
        q_out, mu_out, xm,
        nullptr, nullptr, nullptr, nullptr);
}

// Round 6
// 444.339 us; speedup vs baseline: 1.4540x; 1.0051x over previous
//
#include <hip/hip_runtime.h>
#include <math.h>

#define NA 10000
#define NE 250000
#define FD 128
#define NRBF 20
#define RCUT 5.0f

typedef _Float16 h16;
typedef __attribute__((ext_vector_type(8))) _Float16 half8;
typedef __attribute__((ext_vector_type(2))) _Float16 half2v;
typedef __attribute__((ext_vector_type(4))) float f32x4;

static __device__ __forceinline__ half8 f32x8_to_h8(const float* p) {
    float4 a = *(const float4*)p;
    float4 b = *(const float4*)(p + 4);
    half8 r;
    r[0] = (h16)a.x; r[1] = (h16)a.y; r[2] = (h16)a.z; r[3] = (h16)a.w;
    r[4] = (h16)b.x; r[5] = (h16)b.y; r[6] = (h16)b.z; r[7] = (h16)b.w;
    return r;
}
static __device__ __forceinline__ float silu(float v) {
    return v / (1.f + expf(-v));
}

// ====== mega setup: geom | csr | weight transposes | filter prep ======
// ed[e] = one 64B row: 24 h16 (20 gauss*fcut, fcut, 3 zero) + float4 dir.
__global__ __launch_bounds__(256) void setup_kernel(
    const float* __restrict__ R, const int* __restrict__ idx_i,
    const int* __restrict__ idx_j, const float* __restrict__ offsets,
    h16* __restrict__ ed, int* __restrict__ row_start,
    const float* __restrict__ int_W1, const float* __restrict__ int_W2,
    const float* __restrict__ mix_Wmu, const float* __restrict__ mix_W1,
    const float* __restrict__ mix_W2,
    h16* __restrict__ W1t, h16* __restrict__ W2t, h16* __restrict__ WmuT,
    h16* __restrict__ mW1t, h16* __restrict__ mW2t,
    const float* __restrict__ filt_W, const float* __restrict__ filt_b,
    h16* __restrict__ fwt)
{
    const int b = blockIdx.x;
    if (b < 977) {
        int e = b * 256 + threadIdx.x;
        if (e >= NE) return;
        int i = idx_i[e], j = idx_j[e];
        float rx = R[j * 3 + 0] - R[i * 3 + 0] + offsets[e * 3 + 0];
        float ry = R[j * 3 + 1] - R[i * 3 + 1] + offsets[e * 3 + 1];
        float rz = R[j * 3 + 2] - R[i * 3 + 2] + offsets[e * 3 + 2];
        float d = sqrtf(rx * rx + ry * ry + rz * rz);
        float inv = 1.f / d;
        float fcut = 0.f;
        if (d < RCUT) fcut = 0.5f * (cosf(d * (3.14159265358979323846f / RCUT)) + 1.f);
        h16* pp = ed + (size_t)e * 32;
        const float delta = RCUT / 19.f;
        const float coeff = -0.5f / (delta * delta);
#pragma unroll
        for (int r = 0; r < NRBF; ++r) {
            float dc = d - (float)r * delta;
            pp[r] = (h16)(expf(coeff * dc * dc) * fcut);
        }
        pp[20] = (h16)fcut;
        pp[21] = (h16)0.f; pp[22] = (h16)0.f; pp[23] = (h16)0.f;
        *(float4*)(pp + 24) = make_float4(rx * inv, ry * inv, rz * inv, 0.f);
    } else if (b < 1017) {
        int n = (b - 977) * 256 + threadIdx.x;
        if (n > NA) return;
        int lo = 0, hi = NE;
        while (lo < hi) {
            int mid = (lo + hi) >> 1;
            if (idx_i[mid] < n) lo = mid + 1; else hi = mid;
        }
        row_start[n] = lo;
    } else {
        int idx = (b - 1017) * 256 + threadIdx.x;
        if (idx < 49152) {                       // int_W1: K=128,N=128
            int bt = idx >> 14, rem = idx & 16383;
            int nn = rem >> 7, kk = rem & 127;
            W1t[idx] = (h16)int_W1[(size_t)bt * 16384 + kk * 128 + nn];
        } else if ((idx -= 49152) < 147456) {    // int_W2: K=128,N=384
            int bt = idx / 49152, rem = idx - bt * 49152;
            int nn = rem >> 7, kk = rem & 127;
            W2t[idx] = (h16)int_W2[(size_t)bt * 49152 + kk * 384 + nn];
        } else if ((idx -= 147456) < 98304) {    // mix_Wmu: K=128,N=256
            int bt = idx >> 15, rem = idx & 32767;
            int nn = rem >> 7, kk = rem & 127;
            WmuT[idx] = (h16)mix_Wmu[(size_t)bt * 32768 + kk * 256 + nn];
        } else if ((idx -= 98304) < 98304) {     // mix_W1: K=256,N=128
            int bt = idx >> 15, rem = idx & 32767;
            int nn = rem >> 8, kk = rem & 255;
            mW1t[idx] = (h16)mix_W1[(size_t)bt * 32768 + kk * 128 + nn];
        } else if ((idx -= 98304) < 147456) {    // mix_W2: K=128,N=384
            int bt = idx / 49152, rem = idx - bt * 49152;
            int nn = rem >> 7, kk = rem & 127;
            mW2t[idx] = (h16)mix_W2[(size_t)bt * 49152 + kk * 384 + nn];
        } else if ((idx -= 147456) < 12288) {    // fwt [384][32]
            int nn = idx >> 5, kk = idx & 31;
            float v = 0.f;
            if (kk < 20) v = filt_W[kk * 384 + nn];
            else if (kk == 20) v = filt_b[nn];
            fwt[idx] = (h16)v;
        }
    }
}

// ====== iteration-0 interaction MLP: q = emb[Z]; x = silu(q@W1+b1)@W2+b2 ==
// Writes COMPACT x01c[atom][128][2] = (x0,x1) only — iter-0 edge<false>
// never uses x2 (mu=0); 4B/lane gather rows.
__global__ __launch_bounds__(256) void intmlp0_kernel(
    const int* __restrict__ Z, const float* __restrict__ emb, float* __restrict__ q,
    const h16* __restrict__ W1t, const float* __restrict__ b1,
    const h16* __restrict__ W2t, const float* __restrict__ b2, h16* __restrict__ x01c)
{
    __shared__ h16 Hs[16 * 136];
    const int tid = threadIdx.x;
    const int wave = tid >> 6, lane = tid & 63;
    const int ar = lane & 15, kg = lane >> 4;
    const size_t row0 = (size_t)blockIdx.x * 16;

    {
        int a = tid >> 4, f0 = (tid & 15) * 8;
        const float* src = emb + (size_t)Z[row0 + a] * 128 + f0;
        float4 v0 = *(const float4*)src;
        float4 v1 = *(const float4*)(src + 4);
        *(float4*)&q[(row0 + a) * 128 + f0] = v0;
        *(float4*)&q[(row0 + a) * 128 + f0 + 4] = v1;
    }
    const int zr = Z[row0 + ar];
    f32x4 a1[2] = {};
    for (int ks = 0; ks < 128; ks += 32) {
        int k = ks + kg * 8;
        half8 af = f32x8_to_h8(emb + (size_t)zr * 128 + k);
#pragma unroll
        for (int tt = 0; tt < 2; ++tt) {
            int t = wave * 2 + tt;
            half8 bf = *(const half8*)&W1t[(size_t)(t * 16 + ar) * 128 + k];
            a1[tt] = __builtin_amdgcn_mfma_f32_16x16x32_f16(af, bf, a1[tt], 0, 0, 0);
        }
    }
#pragma unroll
    for (int tt = 0; tt < 2; ++tt) {
        int col = (wave * 2 + tt) * 16 + ar;
        float bb = b1[col];
#pragma unroll
        for (int r = 0; r < 4; ++r)
            Hs[(kg * 4 + r) * 136 + col] = (h16)silu(a1[tt][r] + bb);
    }
    __syncthreads();
    f32x4 a2[6] = {};
    for (int ks = 0; ks < 128; ks += 32) {
        int k = ks + kg * 8;
        half8 af = *(const half8*)&Hs[ar * 136 + k];
#pragma unroll
        for (int tt = 0; tt < 6; ++tt) {
            int t = wave * 6 + tt;
            half8 bf = *(const half8*)&W2t[(size_t)(t * 16 + ar) * 128 + k];
            a2[tt] = __builtin_amdgcn_mfma_f32_16x16x32_f16(af, bf, a2[tt], 0, 0, 0);
        }
    }
#pragma unroll
    for (int tt = 0; tt < 6; ++tt) {
        int col = (wave * 6 + tt) * 16 + ar;
        if (col < 256) {                         // x2 (col>=256) unused at iter 0
            float bb = b2[col];
            int slot = col >> 7, ff = col & 127;
#pragma unroll
            for (int r = 0; r < 4; ++r)
                x01c[((row0 + kg * 4 + r) * 128 + ff) * 2 + slot] = (h16)(a2[tt][r] + bb);
        }
    }
}

// ====== edge kernel: round-2 body; LDS j-list + scalar row base +
// depth-2 gather pipeline ======
// The per-edge dependent chain was idx_j load (~100-200cy) -> xm gather
// (~500-900cy), covered by only 1-deep prefetch => VALUBusy stuck at 62%.
// Now: j staged in LDS per 128-edge chunk (kills the global j load),
// readfirstlane makes the row base scalar (SALU addr math), and the gather
// for e+2 is in flight while computing e (2x latency coverage).
template<bool HAS_MU>
__global__ __launch_bounds__(128, 4) void edge_kernel(
    const h16* __restrict__ ed, const h16* __restrict__ fwt,
    const int* __restrict__ row_start, const int* __restrict__ idx_j,
    const h16* __restrict__ gat, const float* __restrict__ mup,
    float* __restrict__ mun, h16* __restrict__ mu16n, float* __restrict__ q)
{
    const int n = blockIdx.x, f = threadIdx.x;
    __shared__ int js[128];
    half8 FA[3], FB[3], FC[3];
    {
        const half8* pa = (const half8*)(fwt + (size_t)f * 32);
        const half8* pb = (const half8*)(fwt + (size_t)(128 + f) * 32);
#pragma unroll
        for (int r = 0; r < 3; ++r) { FA[r] = pa[r]; FB[r] = pb[r]; }
        if (HAS_MU) {
            const half8* pc = (const half8*)(fwt + (size_t)(256 + f) * 32);
#pragma unroll
            for (int r = 0; r < 3; ++r) FC[r] = pc[r];
        }
    }
    asm volatile("" : "+v"(FA[0]), "+v"(FA[1]), "+v"(FA[2]),
                      "+v"(FB[0]), "+v"(FB[1]), "+v"(FB[2]));
    if (HAS_MU)
        asm volatile("" : "+v"(FC[0]), "+v"(FC[1]), "+v"(FC[2]));

    half2v fa[12], fb[12], fc[12];
    *(half8*)&fa[0] = FA[0]; *(half8*)&fa[4] = FA[1]; *(half8*)&fa[8] = FA[2];
    *(half8*)&fb[0] = FB[0]; *(half8*)&fb[4] = FB[1]; *(half8*)&fb[8] = FB[2];
    if (HAS_MU) {
        *(half8*)&fc[0] = FC[0]; *(half8*)&fc[4] = FC[1]; *(half8*)&fc[8] = FC[2];
    }

    const size_t rstr = HAS_MU ? 768 : 256;      // h16 units per gather row
    const int foff = HAS_MU ? f * 6 : f * 2;     // per-lane h16 offset in row
    float accq = 0.f, am0 = 0.f, am1 = 0.f, am2 = 0.f;
    const int e0 = row_start[n], e1 = row_start[n + 1];

    for (int c0 = e0; c0 < e1; c0 += 128) {
        const int clen = (e1 - c0 < 128) ? (e1 - c0) : 128;
        __syncthreads();                          // protect js across chunks
        if (f < clen) js[f] = idx_j[c0 + f];
        __syncthreads();

        // depth-2 gather prologue (A = edge t=0, B = edge t=1)
        int jA = __builtin_amdgcn_readfirstlane(js[0]);
        const unsigned* gp = (const unsigned*)(gat + (size_t)jA * rstr + foff);
        unsigned a0 = gp[0], a1 = 0u, a2 = 0u;
        if (HAS_MU) { a1 = gp[1]; a2 = gp[2]; }
        unsigned b0 = a0, b1 = a1, b2 = a2;
        if (clen > 1) {
            int jB = __builtin_amdgcn_readfirstlane(js[1]);
            const unsigned* gq = (const unsigned*)(gat + (size_t)jB * rstr + foff);
            b0 = gq[0];
            if (HAS_MU) { b1 = gq[1]; b2 = gq[2]; }
        }
        // ed row prologue (edge t=0)
        const h16* pb8 = ed + (size_t)c0 * 32;
        half8 p0n = *(const half8*)pb8;
        half8 p1n = *(const half8*)(pb8 + 8);
        half8 p2n = *(const half8*)(pb8 + 16);
        float4 dn = *(const float4*)(pb8 + 24);

        for (int t = 0; t < clen; ++t) {
            unsigned g0 = a0, g1 = a1, g2 = a2;
            a0 = b0; a1 = b1; a2 = b2;
            // issue gather for t+2 (clamped at chunk tail)
            int t2 = (t + 2 < clen) ? t + 2 : clen - 1;
            int jC = __builtin_amdgcn_readfirstlane(js[t2]);
            const unsigned* gr = (const unsigned*)(gat + (size_t)jC * rstr + foff);
            b0 = gr[0];
            if (HAS_MU) { b1 = gr[1]; b2 = gr[2]; }
            half8 p0 = p0n, p1 = p1n, p2 = p2n;
            float4 g = dn;
            // issue ed row for t+1 (clamped)
            int tp = (t + 1 < clen) ? t + 1 : clen - 1;
            const h16* pb2 = ed + (size_t)(c0 + tp) * 32;
            p0n = *(const half8*)pb2;
            p1n = *(const half8*)(pb2 + 8);
            p2n = *(const half8*)(pb2 + 16);
            dn = *(const float4*)(pb2 + 24);
            // ---- compute on current edge (round-2 body, do not touch) ----
            half2v pr[12];
            *(half8*)&pr[0] = p0; *(half8*)&pr[4] = p1; *(half8*)&pr[8] = p2;
            half2v A0 = {(h16)0.f, (h16)0.f}, A1 = A0, A2 = A0;
#pragma unroll
            for (int r = 0; r < 11; ++r) {
                A0 = pr[r] * fa[r] + A0;
                A1 = pr[r] * fb[r] + A1;
                if (HAS_MU) A2 = pr[r] * fc[r] + A2;
            }
            float w0 = (float)A0[0] + (float)A0[1];
            float w1 = (float)A1[0] + (float)A1[1];
            half2v h01 = __builtin_bit_cast(half2v, g0);
            half2v h23 = __builtin_bit_cast(half2v, g1);
            float x0 = (float)h01[0], x1 = (float)h01[1];
            accq = fmaf(w0, x0, accq);
            float xw1 = w1 * x1;
            if (HAS_MU) {
                float w2 = (float)A2[0] + (float)A2[1];
                half2v h45 = __builtin_bit_cast(half2v, g2);
                float x2 = (float)h23[0];
                float xw2 = w2 * x2;
                am0 += xw1 * g.x + xw2 * (float)h23[1];
                am1 += xw1 * g.y + xw2 * (float)h45[0];
                am2 += xw1 * g.z + xw2 * (float)h45[1];
            } else {
                am0 = fmaf(xw1, g.x, am0);
                am1 = fmaf(xw1, g.y, am1);
                am2 = fmaf(xw1, g.z, am2);
            }
        }
    }

    q[(size_t)n * FD + f] += accq;
    size_t b = (size_t)n * 384;
    float m0 = (HAS_MU ? mup[b + f] : 0.f) + am0;
    float m1 = (HAS_MU ? mup[b + 128 + f] : 0.f) + am1;
    float m2 = (HAS_MU ? mup[b + 256 + f] : 0.f) + am2;
    mun[b + f] = m0; mun[b + 128 + f] = m1; mun[b + 256 + f] = m2;
    mu16n[b + f] = (h16)m0; mu16n[b + 128 + f] = (h16)m1; mu16n[b + 256 + f] = (h16)m2;
}

// ====== fused mixing (+ optional next-iteration interaction MLP) ======
__global__ __launch_bounds__(256) void mixint_kernel(
    const h16* __restrict__ mu16n, const h16* __restrict__ WmuT,
    const h16* __restrict__ W1t, const float* __restrict__ b1,
    const h16* __restrict__ W2t, const float* __restrict__ b2,
    float* __restrict__ q, float* __restrict__ mu, h16* __restrict__ xmw,
    const h16* __restrict__ nW1t, const float* __restrict__ nb1,
    const h16* __restrict__ nW2t, const float* __restrict__ nb2)
{
    __shared__ __align__(16) h16 MM[48 * 264];   // reused as XMP in nW branch
    __shared__ h16 CT[16 * 264];
    __shared__ h16 Hs[16 * 136];
    __shared__ h16 XM[16 * 392];
    const int tid = threadIdx.x;
    const int wave = tid >> 6, lane = tid & 63;
    const int ar = lane & 15, kg = lane >> 4;
    const size_t row0 = (size_t)blockIdx.x * 16;

    {
        f32x4 acc[3][4] = {};
        int aloc[3], dloc[3];
#pragma unroll
        for (int rt = 0; rt < 3; ++rt) {
            int rr = rt * 16 + ar;
            aloc[rt] = rr / 3;
            dloc[rt] = rr - 3 * aloc[rt];
        }
        for (int ks = 0; ks < 128; ks += 32) {
            int k = ks + kg * 8;
            half8 afr[3];
#pragma unroll
            for (int rt = 0; rt < 3; ++rt)
                afr[rt] = *(const half8*)&mu16n[(row0 + aloc[rt]) * 384 + dloc[rt] * 128 + k];
#pragma unroll
            for (int ct = 0; ct < 4; ++ct) {
                int cc = wave * 4 + ct;
                half8 bf = *(const half8*)&WmuT[(size_t)(cc * 16 + ar) * 128 + k];
#pragma unroll
                for (int rt = 0; rt < 3; ++rt)
                    acc[rt][ct] = __builtin_amdgcn_mfma_f32_16x16x32_f16(afr[rt], bf, acc[rt][ct], 0, 0, 0);
            }
        }
#pragma unroll
        for (int rt = 0; rt < 3; ++rt)
#pragma unroll
            for (int ct = 0; ct < 4; ++ct) {
                int col = (wave * 4 + ct) * 16 + ar;
#pragma unroll
                for (int r = 0; r < 4; ++r)
                    MM[(rt * 16 + kg * 4 + r) * 264 + col] = (h16)acc[rt][ct][r];
            }
    }
    __syncthreads();

    {
        int a = tid >> 4, fi = (tid & 15) * 8;
        const float* qp = q + (row0 + a) * 128 + fi;
        float4 q0 = *(const float4*)qp;
        float4 q1 = *(const float4*)(qp + 4);
        float qv[8] = {q0.x, q0.y, q0.z, q0.w, q1.x, q1.y, q1.z, q1.w};
#pragma unroll
        for (int jj = 0; jj < 8; ++jj) {
            int ff = fi + jj;
            float v0 = (float)MM[(a * 3 + 0) * 264 + ff];
            float v1 = (float)MM[(a * 3 + 1) * 264 + ff];
            float v2 = (float)MM[(a * 3 + 2) * 264 + ff];
            CT[a * 264 + 128 + ff] = (h16)sqrtf(v0 * v0 + v1 * v1 + v2 * v2 + 1e-8f);
            CT[a * 264 + ff] = (h16)qv[jj];
        }
    }
    __syncthreads();

    {
        f32x4 a1[2] = {};
        for (int ks = 0; ks < 256; ks += 32) {
            int k = ks + kg * 8;
            half8 af = *(const half8*)&CT[ar * 264 + k];
#pragma unroll
            for (int tt = 0; tt < 2; ++tt) {
                int t = wave * 2 + tt;
                half8 bf = *(const half8*)&W1t[(size_t)(t * 16 + ar) * 256 + k];
                a1[tt] = __builtin_amdgcn_mfma_f32_16x16x32_f16(af, bf, a1[tt], 0, 0, 0);
            }
        }
#pragma unroll
        for (int tt = 0; tt < 2; ++tt) {
            int col = (wave * 2 + tt) * 16 + ar;
            float bb = b1[col];
#pragma unroll
            for (int r = 0; r < 4; ++r)
                Hs[(kg * 4 + r) * 136 + col] = (h16)silu(a1[tt][r] + bb);
        }
    }
    __syncthreads();

    {
        f32x4 a2[6] = {};
        for (int ks = 0; ks < 128; ks += 32) {
            int k = ks + kg * 8;
            half8 af = *(const half8*)&Hs[ar * 136 + k];
#pragma unroll
            for (int tt = 0; tt < 6; ++tt) {
                int t = wave * 6 + tt;
                half8 bf = *(const half8*)&W2t[(size_t)(t * 16 + ar) * 128 + k];
                a2[tt] = __builtin_amdgcn_mfma_f32_16x16x32_f16(af, bf, a2[tt], 0, 0, 0);
            }
        }
#pragma unroll
        for (int tt = 0; tt < 6; ++tt) {
            int col = (wave * 6 + tt) * 16 + ar;
            float bb = b2[col];
#pragma unroll
            for (int r = 0; r < 4; ++r)
                XM[(kg * 4 + r) * 392 + col] = (h16)(a2[tt][r] + bb);
        }
    }
    __syncthreads();

    h16 mh[24];   // per-thread staged mu16, flushed in nW branch
    {
        int a = tid >> 4, fi = (tid & 15) * 8;
        size_t n = row0 + a;
#pragma unroll
        for (int jj = 0; jj < 8; ++jj) {
            int ff = fi + jj;
            float dq  = (float)XM[a * 392 + ff];
            float dm  = (float)XM[a * 392 + 128 + ff];
            float dqm = (float)XM[a * 392 + 256 + ff];
            float v0 = (float)MM[(a * 3 + 0) * 264 + ff], w0 = (float)MM[(a * 3 + 0) * 264 + 128 + ff];
            float v1 = (float)MM[(a * 3 + 1) * 264 + ff], w1 = (float)MM[(a * 3 + 1) * 264 + 128 + ff];
            float v2 = (float)MM[(a * 3 + 2) * 264 + ff], w2 = (float)MM[(a * 3 + 2) * 264 + 128 + ff];
            float sv = v0 * w0 + v1 * w1 + v2 * w2;
            float qn = q[n * 128 + ff] + dq + dqm * sv;
            q[n * 128 + ff] = qn;
            CT[a * 264 + ff] = (h16)qn;
            size_t b = n * 384 + ff;
            float m0 = mu[b] + dm * w0;
            float m1 = mu[b + 128] + dm * w1;
            float m2 = mu[b + 256] + dm * w2;
            mu[b] = m0; mu[b + 128] = m1; mu[b + 256] = m2;
            mh[jj * 3 + 0] = (h16)m0; mh[jj * 3 + 1] = (h16)m1; mh[jj * 3 + 2] = (h16)m2;
        }
    }
    if (!nW1t) return;
    __syncthreads();

    {
        f32x4 a1[2] = {};
        for (int ks = 0; ks < 128; ks += 32) {
            int k = ks + kg * 8;
            half8 af = *(const half8*)&CT[ar * 264 + k];
#pragma unroll
            for (int tt = 0; tt < 2; ++tt) {
                int t = wave * 2 + tt;
                half8 bf = *(const half8*)&nW1t[(size_t)(t * 16 + ar) * 128 + k];
                a1[tt] = __builtin_amdgcn_mfma_f32_16x16x32_f16(af, bf, a1[tt], 0, 0, 0);
            }
        }
#pragma unroll
        for (int tt = 0; tt < 2; ++tt) {
            int col = (wave * 2 + tt) * 16 + ar;
            float bb = nb1[col];
#pragma unroll
            for (int r = 0; r < 4; ++r)
                Hs[(kg * 4 + r) * 136 + col] = (h16)silu(a1[tt][r] + bb);
        }
        __syncthreads();
        f32x4 a2[6] = {};
        for (int ks = 0; ks < 128; ks += 32) {
            int k = ks + kg * 8;
            half8 af = *(const half8*)&Hs[ar * 136 + k];
#pragma unroll
            for (int tt = 0; tt < 6; ++tt) {
                int t = wave * 6 + tt;
                half8 bf = *(const half8*)&nW2t[(size_t)(t * 16 + ar) * 128 + k];
                a2[tt] = __builtin_amdgcn_mfma_f32_16x16x32_f16(af, bf, a2[tt], 0, 0, 0);
            }
        }
        h16* XMP = MM;
#pragma unroll
        for (int tt = 0; tt < 6; ++tt) {
            int col = (wave * 6 + tt) * 16 + ar;
            float bb = nb2[col];
            int slot = col >> 7, ff = col & 127;
#pragma unroll
            for (int r = 0; r < 4; ++r)
                XMP[((kg * 4 + r) * 128 + ff) * 6 + slot] = (h16)(a2[tt][r] + bb);
        }
        {
            int a = tid >> 4, fi = (tid & 15) * 8;
#pragma unroll
            for (int jj = 0; jj < 8; ++jj)
#pragma unroll
                for (int s = 0; s < 3; ++s)
                    XMP[(a * 128 + fi + jj) * 6 + 3 + s] = mh[jj * 3 + s];
        }
        __syncthreads();
        {
            const uint4* src = (const uint4*)MM;
            uint4* dst = (uint4*)(xmw + row0 * 768);
#pragma unroll
            for (int i = 0; i < 6; ++i)
                dst[tid + i * 256] = src[tid + i * 256];
        }
    }
}

// ====== launch ======
extern "C" void kernel_launch(void* const* d_in, const int* in_sizes, int n_in,
                              void* d_out, int out_size, void* d_ws, size_t ws_size,
                              hipStream_t stream)
{
    const int*   Z       = (const int*)d_in[0];
    const float* R       = (const float*)d_in[1];
    const int*   idx_i   = (const int*)d_in[2];
    const int*   idx_j   = (const int*)d_in[3];
    const float* offsets = (const float*)d_in[4];
    const float* emb     = (const float*)d_in[5];
    const float* filt_W  = (const float*)d_in[6];
    const float* filt_b  = (const float*)d_in[7];
    const float* int_W1  = (const float*)d_in[8];
    const float* int_b1  = (const float*)d_in[9];
    const float* int_W2  = (const float*)d_in[10];
    const float* int_b2  = (const float*)d_in[11];
    const float* mix_Wmu = (const float*)d_in[12];
    const float* mix_W1  = (const float*)d_in[13];
    const float* mix_b1  = (const float*)d_in[14];
    const float* mix_W2  = (const float*)d_in[15];
    const float* mix_b2  = (const float*)d_in[16];

    float* q_out  = (float*)d_out;
    float* mu_out = (float*)d_out + (size_t)NA * FD;

    char* base = (char*)d_ws;
    size_t o = 0;
    auto alloc = [&](size_t bytes) -> void* {
        void* p = base + o;
        o += (bytes + 255) & ~(size_t)255;
        return p;
    };
    h16*   ed     = (h16*)alloc((size_t)NE * 32 * 2);        // merged ph+dir, 64B/edge
    h16*   xm     = (h16*)alloc((size_t)NA * 128 * 6 * 2);   // packed x+mu for edge gather
    h16*   x01c   = (h16*)alloc((size_t)NA * 128 * 2 * 2);   // compact (x0,x1) for iter-0 edge
    h16*   mu16p  = (h16*)alloc((size_t)NA * 384 * 2);       // planar pre-mix mu
    float* mu_ws  = (float*)alloc((size_t)NA * 384 * 4);
    h16*   W1t    = (h16*)alloc((size_t)3 * 128 * 128 * 2);
    h16*   W2t    = (h16*)alloc((size_t)3 * 384 * 128 * 2);
    h16*   WmuT   = (h16*)alloc((size_t)3 * 256 * 128 * 2);
    h16*   mW1t   = (h16*)alloc((size_t)3 * 128 * 256 * 2);
    h16*   mW2t   = (h16*)alloc((size_t)3 * 384 * 128 * 2);
    h16*   fwt    = (h16*)alloc((size_t)384 * 32 * 2);
    int*   row_st = (int*)alloc((size_t)(NA + 1) * 4);

    setup_kernel<<<3177, 256, 0, stream>>>(R, idx_i, idx_j, offsets, ed, row_st,
                                           int_W1, int_W2, mix_Wmu, mix_W1, mix_W2,
                                           W1t, W2t, WmuT, mW1t, mW2t,
                                           filt_W, filt_b, fwt);

    // iteration 0
    intmlp0_kernel<<<NA / 16, 256, 0, stream>>>(Z, emb, q_out,
                                                W1t, int_b1, W2t, int_b2, x01c);
    edge_kernel<false><<<NA, 128, 0, stream>>>(ed, fwt, row_st, idx_j,
                                               x01c, nullptr, mu_out, mu16p, q_out);
    mixint_kernel<<<NA / 16, 256, 0, stream>>>(
        mu16p, WmuT, mW1t, mix_b1, mW2t, mix_b2, q_out, mu_out, xm,
        W1t + 16384, int_b1 + 128, W2t + 49152, int_b2 + 384);

    // iteration 1
    edge_kernel<true><<<NA, 128, 0, stream>>>(ed, fwt, row_st, idx_j,
                                              xm, mu_out, mu_ws, mu16p, q_out);
    mixint_kernel<<<NA / 16, 256, 0, stream>>>(
        mu16p, WmuT + 32768, mW1t + 32768, mix_b1 + 128, mW2t + 49152, mix_b2 + 384,
        q_out, mu_ws, xm,
        W1t + 32768, int_b1 + 256, W2t + 98304, int_b2 + 768);

    // iteration 2
    edge_kernel<true><<<NA, 128, 0, stream>>>(ed, fwt, row_st, idx_j,
                                              xm, mu_ws, mu_out, mu16p, q_out);
    mixint_kernel<<<NA / 16, 256, 0, stream>>>(
        mu16p, WmuT + 65536, mW1t + 65536, mix_b1 + 256, mW2t + 98304, mix_b2 + 768,
        q_out, mu_out, xm,
        nullptr, nullptr, nullptr, nullptr);
}

// Round 7
// 424.810 us; speedup vs baseline: 1.5208x; 1.0460x over previous
//
#include <hip/hip_runtime.h>
#include <math.h>

#define NA 10000
#define NE 250000
#define FD 128
#define NRBF 20
#define RCUT 5.0f

typedef _Float16 h16;
typedef __attribute__((ext_vector_type(8))) _Float16 half8;
typedef __attribute__((ext_vector_type(2))) _Float16 half2v;
typedef __attribute__((ext_vector_type(4))) float f32x4;

static __device__ __forceinline__ half8 f32x8_to_h8(const float* p) {
    float4 a = *(const float4*)p;
    float4 b = *(const float4*)(p + 4);
    half8 r;
    r[0] = (h16)a.x; r[1] = (h16)a.y; r[2] = (h16)a.z; r[3] = (h16)a.w;
    r[4] = (h16)b.x; r[5] = (h16)b.y; r[6] = (h16)b.z; r[7] = (h16)b.w;
    return r;
}
static __device__ __forceinline__ float silu(float v) {
    return v / (1.f + expf(-v));
}

// ====== mega setup: geom | csr | weight transposes | filter prep ======
// ed[e] = one 64B row: 24 h16 (20 gauss*fcut, fcut, 3 zero) + float4 dir.
__global__ __launch_bounds__(256) void setup_kernel(
    const float* __restrict__ R, const int* __restrict__ idx_i,
    const int* __restrict__ idx_j, const float* __restrict__ offsets,
    h16* __restrict__ ed, int* __restrict__ row_start,
    const float* __restrict__ int_W1, const float* __restrict__ int_W2,
    const float* __restrict__ mix_Wmu, const float* __restrict__ mix_W1,
    const float* __restrict__ mix_W2,
    h16* __restrict__ W1t, h16* __restrict__ W2t, h16* __restrict__ WmuT,
    h16* __restrict__ mW1t, h16* __restrict__ mW2t,
    const float* __restrict__ filt_W, const float* __restrict__ filt_b,
    h16* __restrict__ fwt)
{
    const int b = blockIdx.x;
    if (b < 977) {
        int e = b * 256 + threadIdx.x;
        if (e >= NE) return;
        int i = idx_i[e], j = idx_j[e];
        float rx = R[j * 3 + 0] - R[i * 3 + 0] + offsets[e * 3 + 0];
        float ry = R[j * 3 + 1] - R[i * 3 + 1] + offsets[e * 3 + 1];
        float rz = R[j * 3 + 2] - R[i * 3 + 2] + offsets[e * 3 + 2];
        float d = sqrtf(rx * rx + ry * ry + rz * rz);
        float inv = 1.f / d;
        float fcut = 0.f;
        if (d < RCUT) fcut = 0.5f * (cosf(d * (3.14159265358979323846f / RCUT)) + 1.f);
        h16* pp = ed + (size_t)e * 32;
        const float delta = RCUT / 19.f;
        const float coeff = -0.5f / (delta * delta);
#pragma unroll
        for (int r = 0; r < NRBF; ++r) {
            float dc = d - (float)r * delta;
            pp[r] = (h16)(expf(coeff * dc * dc) * fcut);
        }
        pp[20] = (h16)fcut;
        pp[21] = (h16)0.f; pp[22] = (h16)0.f; pp[23] = (h16)0.f;
        *(float4*)(pp + 24) = make_float4(rx * inv, ry * inv, rz * inv, 0.f);
    } else if (b < 1017) {
        int n = (b - 977) * 256 + threadIdx.x;
        if (n > NA) return;
        int lo = 0, hi = NE;
        while (lo < hi) {
            int mid = (lo + hi) >> 1;
            if (idx_i[mid] < n) lo = mid + 1; else hi = mid;
        }
        row_start[n] = lo;
    } else {
        int idx = (b - 1017) * 256 + threadIdx.x;
        if (idx < 49152) {                       // int_W1: K=128,N=128
            int bt = idx >> 14, rem = idx & 16383;
            int nn = rem >> 7, kk = rem & 127;
            W1t[idx] = (h16)int_W1[(size_t)bt * 16384 + kk * 128 + nn];
        } else if ((idx -= 49152) < 147456) {    // int_W2: K=128,N=384
            int bt = idx / 49152, rem = idx - bt * 49152;
            int nn = rem >> 7, kk = rem & 127;
            W2t[idx] = (h16)int_W2[(size_t)bt * 49152 + kk * 384 + nn];
        } else if ((idx -= 147456) < 98304) {    // mix_Wmu: K=128,N=256
            int bt = idx >> 15, rem = idx & 32767;
            int nn = rem >> 7, kk = rem & 127;
            WmuT[idx] = (h16)mix_Wmu[(size_t)bt * 32768 + kk * 256 + nn];
        } else if ((idx -= 98304) < 98304) {     // mix_W1: K=256,N=128
            int bt = idx >> 15, rem = idx & 32767;
            int nn = rem >> 8, kk = rem & 255;
            mW1t[idx] = (h16)mix_W1[(size_t)bt * 32768 + kk * 128 + nn];
        } else if ((idx -= 98304) < 147456) {    // mix_W2: K=128,N=384
            int bt = idx / 49152, rem = idx - bt * 49152;
            int nn = rem >> 7, kk = rem & 127;
            mW2t[idx] = (h16)mix_W2[(size_t)bt * 49152 + kk * 384 + nn];
        } else if ((idx -= 147456) < 12288) {    // fwt [384][32]
            int nn = idx >> 5, kk = idx & 31;
            float v = 0.f;
            if (kk < 20) v = filt_W[kk * 384 + nn];
            else if (kk == 20) v = filt_b[nn];
            fwt[idx] = (h16)v;
        }
    }
}

// ====== iteration-0 interaction MLP: q = emb[Z]; x = silu(q@W1+b1)@W2+b2 ==
// Writes COMPACT x01c[atom][128][2] = (x0,x1) only — iter-0 edge<false>
// never uses x2 (mu=0); 4B/lane gather rows = half the iter-0 gather bytes.
__global__ __launch_bounds__(256) void intmlp0_kernel(
    const int* __restrict__ Z, const float* __restrict__ emb, float* __restrict__ q,
    const h16* __restrict__ W1t, const float* __restrict__ b1,
    const h16* __restrict__ W2t, const float* __restrict__ b2, h16* __restrict__ x01c)
{
    __shared__ h16 Hs[16 * 136];
    const int tid = threadIdx.x;
    const int wave = tid >> 6, lane = tid & 63;
    const int ar = lane & 15, kg = lane >> 4;
    const size_t row0 = (size_t)blockIdx.x * 16;

    {
        int a = tid >> 4, f0 = (tid & 15) * 8;
        const float* src = emb + (size_t)Z[row0 + a] * 128 + f0;
        float4 v0 = *(const float4*)src;
        float4 v1 = *(const float4*)(src + 4);
        *(float4*)&q[(row0 + a) * 128 + f0] = v0;
        *(float4*)&q[(row0 + a) * 128 + f0 + 4] = v1;
    }
    const int zr = Z[row0 + ar];
    f32x4 a1[2] = {};
    for (int ks = 0; ks < 128; ks += 32) {
        int k = ks + kg * 8;
        half8 af = f32x8_to_h8(emb + (size_t)zr * 128 + k);
#pragma unroll
        for (int tt = 0; tt < 2; ++tt) {
            int t = wave * 2 + tt;
            half8 bf = *(const half8*)&W1t[(size_t)(t * 16 + ar) * 128 + k];
            a1[tt] = __builtin_amdgcn_mfma_f32_16x16x32_f16(af, bf, a1[tt], 0, 0, 0);
        }
    }
#pragma unroll
    for (int tt = 0; tt < 2; ++tt) {
        int col = (wave * 2 + tt) * 16 + ar;
        float bb = b1[col];
#pragma unroll
        for (int r = 0; r < 4; ++r)
            Hs[(kg * 4 + r) * 136 + col] = (h16)silu(a1[tt][r] + bb);
    }
    __syncthreads();
    f32x4 a2[6] = {};
    for (int ks = 0; ks < 128; ks += 32) {
        int k = ks + kg * 8;
        half8 af = *(const half8*)&Hs[ar * 136 + k];
#pragma unroll
        for (int tt = 0; tt < 6; ++tt) {
            int t = wave * 6 + tt;
            half8 bf = *(const half8*)&W2t[(size_t)(t * 16 + ar) * 128 + k];
            a2[tt] = __builtin_amdgcn_mfma_f32_16x16x32_f16(af, bf, a2[tt], 0, 0, 0);
        }
    }
#pragma unroll
    for (int tt = 0; tt < 6; ++tt) {
        int col = (wave * 6 + tt) * 16 + ar;
        if (col < 256) {                         // x2 (col>=256) unused at iter 0
            float bb = b2[col];
            int slot = col >> 7, ff = col & 127;
#pragma unroll
            for (int r = 0; r < 4; ++r)
                x01c[((row0 + kg * 4 + r) * 128 + ff) * 2 + slot] = (h16)(a2[tt][r] + bb);
        }
    }
}

// ====== edge kernel: round-2 proven loop (75.7us), merged 64B ed row ======
// 6 rounds of structural variants (fdot2 restructure, persistent+atomic,
// j-bucketing, LDS j-list + depth-2) all measured >= this config. The
// compiler's schedule of this body — incl. re-loading filter columns from
// the L1-resident 24KB fwt each edge (VGPR=28 is fine, those are L1 hits) —
// is the empirical equilibrium. Do not restructure.
template<bool HAS_MU>
__global__ __launch_bounds__(128, 4) void edge_kernel(
    const h16* __restrict__ ed, const h16* __restrict__ fwt,
    const int* __restrict__ row_start, const int* __restrict__ idx_j,
    const h16* __restrict__ gat, const float* __restrict__ mup,
    float* __restrict__ mun, h16* __restrict__ mu16n, float* __restrict__ q)
{
    const int n = blockIdx.x, f = threadIdx.x;
    half8 FA[3], FB[3], FC[3];
    {
        const half8* pa = (const half8*)(fwt + (size_t)f * 32);
        const half8* pb = (const half8*)(fwt + (size_t)(128 + f) * 32);
#pragma unroll
        for (int r = 0; r < 3; ++r) { FA[r] = pa[r]; FB[r] = pb[r]; }
        if (HAS_MU) {
            const half8* pc = (const half8*)(fwt + (size_t)(256 + f) * 32);
#pragma unroll
            for (int r = 0; r < 3; ++r) FC[r] = pc[r];
        }
    }
    asm volatile("" : "+v"(FA[0]), "+v"(FA[1]), "+v"(FA[2]),
                      "+v"(FB[0]), "+v"(FB[1]), "+v"(FB[2]));
    if (HAS_MU)
        asm volatile("" : "+v"(FC[0]), "+v"(FC[1]), "+v"(FC[2]));

    half2v fa[12], fb[12], fc[12];
    *(half8*)&fa[0] = FA[0]; *(half8*)&fa[4] = FA[1]; *(half8*)&fa[8] = FA[2];
    *(half8*)&fb[0] = FB[0]; *(half8*)&fb[4] = FB[1]; *(half8*)&fb[8] = FB[2];
    if (HAS_MU) {
        *(half8*)&fc[0] = FC[0]; *(half8*)&fc[4] = FC[1]; *(half8*)&fc[8] = FC[2];
    }

    const size_t rstr = HAS_MU ? 768 : 256;      // h16 units per gather row
    const h16* xmf = gat + (HAS_MU ? (size_t)f * 6 : (size_t)f * 2);
    float accq = 0.f, am0 = 0.f, am1 = 0.f, am2 = 0.f;
    const int e0 = row_start[n], e1 = row_start[n + 1];
    if (e0 < e1) {
        // prologue prefetch for edge e0
        int j = idx_j[e0];
        const unsigned* gp = (const unsigned*)(xmf + (size_t)j * rstr);
        unsigned g0n = gp[0], g1n = 0u, g2n = 0u;
        if (HAS_MU) { g1n = gp[1]; g2n = gp[2]; }
        const h16* pb8 = ed + (size_t)e0 * 32;
        half8 p0n = *(const half8*)pb8;
        half8 p1n = *(const half8*)(pb8 + 8);
        half8 p2n = *(const half8*)(pb8 + 16);
        float4 dn = *(const float4*)(pb8 + 24);
        for (int e = e0; e < e1; ++e) {
            unsigned g0 = g0n, g1 = g1n, g2 = g2n;
            half8 p0 = p0n, p1 = p1n, p2 = p2n;
            float4 g = dn;
            // prefetch e+1 (clamped: last iteration redundantly re-fetches e)
            int ep = (e + 1 < e1) ? e + 1 : e;
            int j2 = idx_j[ep];
            const unsigned* gp2 = (const unsigned*)(xmf + (size_t)j2 * rstr);
            g0n = gp2[0];
            if (HAS_MU) { g1n = gp2[1]; g2n = gp2[2]; }
            const h16* pb2 = ed + (size_t)ep * 32;
            p0n = *(const half8*)pb2;
            p1n = *(const half8*)(pb2 + 8);
            p2n = *(const half8*)(pb2 + 16);
            dn = *(const float4*)(pb2 + 24);
            // ---- compute on current edge ----
            half2v pr[12];
            *(half8*)&pr[0] = p0; *(half8*)&pr[4] = p1; *(half8*)&pr[8] = p2;
            half2v A0 = {(h16)0.f, (h16)0.f}, A1 = A0, A2 = A0;
#pragma unroll
            for (int r = 0; r < 11; ++r) {
                A0 = pr[r] * fa[r] + A0;
                A1 = pr[r] * fb[r] + A1;
                if (HAS_MU) A2 = pr[r] * fc[r] + A2;
            }
            float w0 = (float)A0[0] + (float)A0[1];
            float w1 = (float)A1[0] + (float)A1[1];
            half2v h01 = __builtin_bit_cast(half2v, g0);
            half2v h23 = __builtin_bit_cast(half2v, g1);
            float x0 = (float)h01[0], x1 = (float)h01[1];
            accq = fmaf(w0, x0, accq);
            float xw1 = w1 * x1;
            if (HAS_MU) {
                float w2 = (float)A2[0] + (float)A2[1];
                half2v h45 = __builtin_bit_cast(half2v, g2);
                float x2 = (float)h23[0];
                float xw2 = w2 * x2;
                am0 += xw1 * g.x + xw2 * (float)h23[1];
                am1 += xw1 * g.y + xw2 * (float)h45[0];
                am2 += xw1 * g.z + xw2 * (float)h45[1];
            } else {
                am0 = fmaf(xw1, g.x, am0);
                am1 = fmaf(xw1, g.y, am1);
                am2 = fmaf(xw1, g.z, am2);
            }
        }
    }

    q[(size_t)n * FD + f] += accq;
    size_t b = (size_t)n * 384;
    float m0 = (HAS_MU ? mup[b + f] : 0.f) + am0;
    float m1 = (HAS_MU ? mup[b + 128 + f] : 0.f) + am1;
    float m2 = (HAS_MU ? mup[b + 256 + f] : 0.f) + am2;
    mun[b + f] = m0; mun[b + 128 + f] = m1; mun[b + 256 + f] = m2;
    mu16n[b + f] = (h16)m0; mu16n[b + 128 + f] = (h16)m1; mu16n[b + 256 + f] = (h16)m2;
}

// ====== fused mixing (+ optional next-iteration interaction MLP) ======
__global__ __launch_bounds__(256) void mixint_kernel(
    const h16* __restrict__ mu16n, const h16* __restrict__ WmuT,
    const h16* __restrict__ W1t, const float* __restrict__ b1,
    const h16* __restrict__ W2t, const float* __restrict__ b2,
    float* __restrict__ q, float* __restrict__ mu, h16* __restrict__ xmw,
    const h16* __restrict__ nW1t, const float* __restrict__ nb1,
    const h16* __restrict__ nW2t, const float* __restrict__ nb2)
{
    __shared__ __align__(16) h16 MM[48 * 264];   // reused as XMP in nW branch
    __shared__ h16 CT[16 * 264];
    __shared__ h16 Hs[16 * 136];
    __shared__ h16 XM[16 * 392];
    const int tid = threadIdx.x;
    const int wave = tid >> 6, lane = tid & 63;
    const int ar = lane & 15, kg = lane >> 4;
    const size_t row0 = (size_t)blockIdx.x * 16;

    {
        f32x4 acc[3][4] = {};
        int aloc[3], dloc[3];
#pragma unroll
        for (int rt = 0; rt < 3; ++rt) {
            int rr = rt * 16 + ar;
            aloc[rt] = rr / 3;
            dloc[rt] = rr - 3 * aloc[rt];
        }
        for (int ks = 0; ks < 128; ks += 32) {
            int k = ks + kg * 8;
            half8 afr[3];
#pragma unroll
            for (int rt = 0; rt < 3; ++rt)
                afr[rt] = *(const half8*)&mu16n[(row0 + aloc[rt]) * 384 + dloc[rt] * 128 + k];
#pragma unroll
            for (int ct = 0; ct < 4; ++ct) {
                int cc = wave * 4 + ct;
                half8 bf = *(const half8*)&WmuT[(size_t)(cc * 16 + ar) * 128 + k];
#pragma unroll
                for (int rt = 0; rt < 3; ++rt)
                    acc[rt][ct] = __builtin_amdgcn_mfma_f32_16x16x32_f16(afr[rt], bf, acc[rt][ct], 0, 0, 0);
            }
        }
#pragma unroll
        for (int rt = 0; rt < 3; ++rt)
#pragma unroll
            for (int ct = 0; ct < 4; ++ct) {
                int col = (wave * 4 + ct) * 16 + ar;
#pragma unroll
                for (int r = 0; r < 4; ++r)
                    MM[(rt * 16 + kg * 4 + r) * 264 + col] = (h16)acc[rt][ct][r];
            }
    }
    __syncthreads();

    {
        int a = tid >> 4, fi = (tid & 15) * 8;
        const float* qp = q + (row0 + a) * 128 + fi;
        float4 q0 = *(const float4*)qp;
        float4 q1 = *(const float4*)(qp + 4);
        float qv[8] = {q0.x, q0.y, q0.z, q0.w, q1.x, q1.y, q1.z, q1.w};
#pragma unroll
        for (int jj = 0; jj < 8; ++jj) {
            int ff = fi + jj;
            float v0 = (float)MM[(a * 3 + 0) * 264 + ff];
            float v1 = (float)MM[(a * 3 + 1) * 264 + ff];
            float v2 = (float)MM[(a * 3 + 2) * 264 + ff];
            CT[a * 264 + 128 + ff] = (h16)sqrtf(v0 * v0 + v1 * v1 + v2 * v2 + 1e-8f);
            CT[a * 264 + ff] = (h16)qv[jj];
        }
    }
    __syncthreads();

    {
        f32x4 a1[2] = {};
        for (int ks = 0; ks < 256; ks += 32) {
            int k = ks + kg * 8;
            half8 af = *(const half8*)&CT[ar * 264 + k];
#pragma unroll
            for (int tt = 0; tt < 2; ++tt) {
                int t = wave * 2 + tt;
                half8 bf = *(const half8*)&W1t[(size_t)(t * 16 + ar) * 256 + k];
                a1[tt] = __builtin_amdgcn_mfma_f32_16x16x32_f16(af, bf, a1[tt], 0, 0, 0);
            }
        }
#pragma unroll
        for (int tt = 0; tt < 2; ++tt) {
            int col = (wave * 2 + tt) * 16 + ar;
            float bb = b1[col];
#pragma unroll
            for (int r = 0; r < 4; ++r)
                Hs[(kg * 4 + r) * 136 + col] = (h16)silu(a1[tt][r] + bb);
        }
    }
    __syncthreads();

    {
        f32x4 a2[6] = {};
        for (int ks = 0; ks < 128; ks += 32) {
            int k = ks + kg * 8;
            half8 af = *(const half8*)&Hs[ar * 136 + k];
#pragma unroll
            for (int tt = 0; tt < 6; ++tt) {
                int t = wave * 6 + tt;
                half8 bf = *(const half8*)&W2t[(size_t)(t * 16 + ar) * 128 + k];
                a2[tt] = __builtin_amdgcn_mfma_f32_16x16x32_f16(af, bf, a2[tt], 0, 0, 0);
            }
        }
#pragma unroll
        for (int tt = 0; tt < 6; ++tt) {
            int col = (wave * 6 + tt) * 16 + ar;
            float bb = b2[col];
#pragma unroll
            for (int r = 0; r < 4; ++r)
                XM[(kg * 4 + r) * 392 + col] = (h16)(a2[tt][r] + bb);
        }
    }
    __syncthreads();

    h16 mh[24];   // per-thread staged mu16, flushed in nW branch
    {
        int a = tid >> 4, fi = (tid & 15) * 8;
        size_t n = row0 + a;
#pragma unroll
        for (int jj = 0; jj < 8; ++jj) {
            int ff = fi + jj;
            float dq  = (float)XM[a * 392 + ff];
            float dm  = (float)XM[a * 392 + 128 + ff];
            float dqm = (float)XM[a * 392 + 256 + ff];
            float v0 = (float)MM[(a * 3 + 0) * 264 + ff], w0 = (float)MM[(a * 3 + 0) * 264 + 128 + ff];
            float v1 = (float)MM[(a * 3 + 1) * 264 + ff], w1 = (float)MM[(a * 3 + 1) * 264 + 128 + ff];
            float v2 = (float)MM[(a * 3 + 2) * 264 + ff], w2 = (float)MM[(a * 3 + 2) * 264 + 128 + ff];
            float sv = v0 * w0 + v1 * w1 + v2 * w2;
            float qn = q[n * 128 + ff] + dq + dqm * sv;
            q[n * 128 + ff] = qn;
            CT[a * 264 + ff] = (h16)qn;
            size_t b = n * 384 + ff;
            float m0 = mu[b] + dm * w0;
            float m1 = mu[b + 128] + dm * w1;
            float m2 = mu[b + 256] + dm * w2;
            mu[b] = m0; mu[b + 128] = m1; mu[b + 256] = m2;
            mh[jj * 3 + 0] = (h16)m0; mh[jj * 3 + 1] = (h16)m1; mh[jj * 3 + 2] = (h16)m2;
        }
    }
    if (!nW1t) return;
    __syncthreads();

    {
        f32x4 a1[2] = {};
        for (int ks = 0; ks < 128; ks += 32) {
            int k = ks + kg * 8;
            half8 af = *(const half8*)&CT[ar * 264 + k];
#pragma unroll
            for (int tt = 0; tt < 2; ++tt) {
                int t = wave * 2 + tt;
                half8 bf = *(const half8*)&nW1t[(size_t)(t * 16 + ar) * 128 + k];
                a1[tt] = __builtin_amdgcn_mfma_f32_16x16x32_f16(af, bf, a1[tt], 0, 0, 0);
            }
        }
#pragma unroll
        for (int tt = 0; tt < 2; ++tt) {
            int col = (wave * 2 + tt) * 16 + ar;
            float bb = nb1[col];
#pragma unroll
            for (int r = 0; r < 4; ++r)
                Hs[(kg * 4 + r) * 136 + col] = (h16)silu(a1[tt][r] + bb);
        }
        __syncthreads();
        f32x4 a2[6] = {};
        for (int ks = 0; ks < 128; ks += 32) {
            int k = ks + kg * 8;
            half8 af = *(const half8*)&Hs[ar * 136 + k];
#pragma unroll
            for (int tt = 0; tt < 6; ++tt) {
                int t = wave * 6 + tt;
                half8 bf = *(const half8*)&nW2t[(size_t)(t * 16 + ar) * 128 + k];
                a2[tt] = __builtin_amdgcn_mfma_f32_16x16x32_f16(af, bf, a2[tt], 0, 0, 0);
            }
        }
        h16* XMP = MM;
#pragma unroll
        for (int tt = 0; tt < 6; ++tt) {
            int col = (wave * 6 + tt) * 16 + ar;
            float bb = nb2[col];
            int slot = col >> 7, ff = col & 127;
#pragma unroll
            for (int r = 0; r < 4; ++r)
                XMP[((kg * 4 + r) * 128 + ff) * 6 + slot] = (h16)(a2[tt][r] + bb);
        }
        {
            int a = tid >> 4, fi = (tid & 15) * 8;
#pragma unroll
            for (int jj = 0; jj < 8; ++jj)
#pragma unroll
                for (int s = 0; s < 3; ++s)
                    XMP[(a * 128 + fi + jj) * 6 + 3 + s] = mh[jj * 3 + s];
        }
        __syncthreads();
        {
            const uint4* src = (const uint4*)MM;
            uint4* dst = (uint4*)(xmw + row0 * 768);
#pragma unroll
            for (int i = 0; i < 6; ++i)
                dst[tid + i * 256] = src[tid + i * 256];
        }
    }
}

// ====== launch ======
extern "C" void kernel_launch(void* const* d_in, const int* in_sizes, int n_in,
                              void* d_out, int out_size, void* d_ws, size_t ws_size,
                              hipStream_t stream)
{
    const int*   Z       = (const int*)d_in[0];
    const float* R       = (const float*)d_in[1];
    const int*   idx_i   = (const int*)d_in[2];
    const int*   idx_j   = (const int*)d_in[3];
    const float* offsets = (const float*)d_in[4];
    const float* emb     = (const float*)d_in[5];
    const float* filt_W  = (const float*)d_in[6];
    const float* filt_b  = (const float*)d_in[7];
    const float* int_W1  = (const float*)d_in[8];
    const float* int_b1  = (const float*)d_in[9];
    const float* int_W2  = (const float*)d_in[10];
    const float* int_b2  = (const float*)d_in[11];
    const float* mix_Wmu = (const float*)d_in[12];
    const float* mix_W1  = (const float*)d_in[13];
    const float* mix_b1  = (const float*)d_in[14];
    const float* mix_W2  = (const float*)d_in[15];
    const float* mix_b2  = (const float*)d_in[16];

    float* q_out  = (float*)d_out;
    float* mu_out = (float*)d_out + (size_t)NA * FD;

    char* base = (char*)d_ws;
    size_t o = 0;
    auto alloc = [&](size_t bytes) -> void* {
        void* p = base + o;
        o += (bytes + 255) & ~(size_t)255;
        return p;
    };
    h16*   ed     = (h16*)alloc((size_t)NE * 32 * 2);        // merged ph+dir, 64B/edge
    h16*   xm     = (h16*)alloc((size_t)NA * 128 * 6 * 2);   // packed x+mu for edge gather
    h16*   x01c   = (h16*)alloc((size_t)NA * 128 * 2 * 2);   // compact (x0,x1) for iter-0 edge
    h16*   mu16p  = (h16*)alloc((size_t)NA * 384 * 2);       // planar pre-mix mu
    float* mu_ws  = (float*)alloc((size_t)NA * 384 * 4);
    h16*   W1t    = (h16*)alloc((size_t)3 * 128 * 128 * 2);
    h16*   W2t    = (h16*)alloc((size_t)3 * 384 * 128 * 2);
    h16*   WmuT   = (h16*)alloc((size_t)3 * 256 * 128 * 2);
    h16*   mW1t   = (h16*)alloc((size_t)3 * 128 * 256 * 2);
    h16*   mW2t   = (h16*)alloc((size_t)3 * 384 * 128 * 2);
    h16*   fwt    = (h16*)alloc((size_t)384 * 32 * 2);
    int*   row_st = (int*)alloc((size_t)(NA + 1) * 4);

    setup_kernel<<<3177, 256, 0, stream>>>(R, idx_i, idx_j, offsets, ed, row_st,
                                           int_W1, int_W2, mix_Wmu, mix_W1, mix_W2,
                                           W1t, W2t, WmuT, mW1t, mW2t,
                                           filt_W, filt_b, fwt);

    // iteration 0
    intmlp0_kernel<<<NA / 16, 256, 0, stream>>>(Z, emb, q_out,
                                                W1t, int_b1, W2t, int_b2, x01c);
    edge_kernel<false><<<NA, 128, 0, stream>>>(ed, fwt, row_st, idx_j,
                                               x01c, nullptr, mu_out, mu16p, q_out);
    mixint_kernel<<<NA / 16, 256, 0, stream>>>(
        mu16p, WmuT, mW1t, mix_b1, mW2t, mix_b2, q_out, mu_out, xm,
        W1t + 16384, int_b1 + 128, W2t + 49152, int_b2 + 384);

    // iteration 1
    edge_kernel<true><<<NA, 128, 0, stream>>>(ed, fwt, row_st, idx_j,
                                              xm, mu_out, mu_ws, mu16p, q_out);
    mixint_kernel<<<NA / 16, 256, 0, stream>>>(
        mu16p, WmuT + 32768, mW1t + 32768, mix_b1 + 128, mW2t + 49152, mix_b2 + 384,
        q_out, mu_ws, xm,
        W1t + 32768, int_b1 + 256, W2t + 98304, int_b2 + 768);

    // iteration 2
    edge_kernel<true><<<NA, 128, 0, stream>>>(ed, fwt, row_st, idx_j,
                                              xm, mu_ws, mu_out, mu16p, q_out);
    mixint_kernel<<<NA / 16, 256, 0, stream>>>(
        mu16p, WmuT + 65536, mW1t + 65536, mix_b1 + 256, mW2t + 98304, mix_b2 + 768,
        q_out, mu_out, xm,
        nullptr, nullptr, nullptr, nullptr);
}

// Round 8
// 418.371 us; speedup vs baseline: 1.5443x; 1.0154x over previous
//
#include <hip/hip_runtime.h>
#include <math.h>

#define NA 10000
#define NE 250000
#define FD 128
#define NRBF 20
#define RCUT 5.0f

typedef _Float16 h16;
typedef __attribute__((ext_vector_type(8))) _Float16 half8;
typedef __attribute__((ext_vector_type(2))) _Float16 half2v;
typedef __attribute__((ext_vector_type(4))) float f32x4;

static __device__ __forceinline__ half8 f32x8_to_h8(const float* p) {
    float4 a = *(const float4*)p;
    float4 b = *(const float4*)(p + 4);
    half8 r;
    r[0] = (h16)a.x; r[1] = (h16)a.y; r[2] = (h16)a.z; r[3] = (h16)a.w;
    r[4] = (h16)b.x; r[5] = (h16)b.y; r[6] = (h16)b.z; r[7] = (h16)b.w;
    return r;
}
static __device__ __forceinline__ float silu(float v) {
    return v / (1.f + expf(-v));
}

// ====== mega setup: geom | csr | weights | q-init ======
// ed[e] = one 64B row: 20 gauss*fcut, fcut, 0, Zj-bits, 0 (h16) + float4 dir.
// Element 22 carries (ushort)Z[idx_j[e]]: the filter dot loop reads elements
// 0..21 only (r<11 over half2 pairs), so 22/23 are free payload slots.
__global__ __launch_bounds__(256) void setup_kernel(
    const float* __restrict__ R, const int* __restrict__ idx_i,
    const int* __restrict__ idx_j, const float* __restrict__ offsets,
    const int* __restrict__ Zt, const float* __restrict__ emb, float* __restrict__ q,
    h16* __restrict__ ed, int* __restrict__ row_start,
    const float* __restrict__ int_W1, const float* __restrict__ int_W2,
    const float* __restrict__ mix_Wmu, const float* __restrict__ mix_W1,
    const float* __restrict__ mix_W2,
    h16* __restrict__ W1t, h16* __restrict__ W2t, h16* __restrict__ WmuT,
    h16* __restrict__ mW1t, h16* __restrict__ mW2t,
    const float* __restrict__ filt_W, const float* __restrict__ filt_b,
    h16* __restrict__ fwt)
{
    const int b = blockIdx.x;
    if (b < 977) {
        int e = b * 256 + threadIdx.x;
        if (e >= NE) return;
        int i = idx_i[e], j = idx_j[e];
        float rx = R[j * 3 + 0] - R[i * 3 + 0] + offsets[e * 3 + 0];
        float ry = R[j * 3 + 1] - R[i * 3 + 1] + offsets[e * 3 + 1];
        float rz = R[j * 3 + 2] - R[i * 3 + 2] + offsets[e * 3 + 2];
        float d = sqrtf(rx * rx + ry * ry + rz * rz);
        float inv = 1.f / d;
        float fcut = 0.f;
        if (d < RCUT) fcut = 0.5f * (cosf(d * (3.14159265358979323846f / RCUT)) + 1.f);
        h16* pp = ed + (size_t)e * 32;
        const float delta = RCUT / 19.f;
        const float coeff = -0.5f / (delta * delta);
#pragma unroll
        for (int r = 0; r < NRBF; ++r) {
            float dc = d - (float)r * delta;
            pp[r] = (h16)(expf(coeff * dc * dc) * fcut);
        }
        pp[20] = (h16)fcut;
        pp[21] = (h16)0.f;
        pp[22] = __builtin_bit_cast(h16, (unsigned short)Zt[j]);
        pp[23] = (h16)0.f;
        *(float4*)(pp + 24) = make_float4(rx * inv, ry * inv, rz * inv, 0.f);
    } else if (b < 1017) {
        int n = (b - 977) * 256 + threadIdx.x;
        if (n > NA) return;
        int lo = 0, hi = NE;
        while (lo < hi) {
            int mid = (lo + hi) >> 1;
            if (idx_i[mid] < n) lo = mid + 1; else hi = mid;
        }
        row_start[n] = lo;
    } else if (b < 3177) {
        int idx = (b - 1017) * 256 + threadIdx.x;
        if (idx < 49152) {                       // int_W1: K=128,N=128
            int bt = idx >> 14, rem = idx & 16383;
            int nn = rem >> 7, kk = rem & 127;
            W1t[idx] = (h16)int_W1[(size_t)bt * 16384 + kk * 128 + nn];
        } else if ((idx -= 49152) < 147456) {    // int_W2: K=128,N=384
            int bt = idx / 49152, rem = idx - bt * 49152;
            int nn = rem >> 7, kk = rem & 127;
            W2t[idx] = (h16)int_W2[(size_t)bt * 49152 + kk * 384 + nn];
        } else if ((idx -= 147456) < 98304) {    // mix_Wmu: K=128,N=256
            int bt = idx >> 15, rem = idx & 32767;
            int nn = rem >> 7, kk = rem & 127;
            WmuT[idx] = (h16)mix_Wmu[(size_t)bt * 32768 + kk * 256 + nn];
        } else if ((idx -= 98304) < 98304) {     // mix_W1: K=256,N=128
            int bt = idx >> 15, rem = idx & 32767;
            int nn = rem >> 8, kk = rem & 255;
            mW1t[idx] = (h16)mix_W1[(size_t)bt * 32768 + kk * 128 + nn];
        } else if ((idx -= 98304) < 147456) {    // mix_W2: K=128,N=384
            int bt = idx / 49152, rem = idx - bt * 49152;
            int nn = rem >> 7, kk = rem & 127;
            mW2t[idx] = (h16)mix_W2[(size_t)bt * 49152 + kk * 384 + nn];
        } else if ((idx -= 147456) < 12288) {    // fwt [384][32]
            int nn = idx >> 5, kk = idx & 31;
            float v = 0.f;
            if (kk < 20) v = filt_W[kk * 384 + nn];
            else if (kk == 20) v = filt_b[nn];
            fwt[idx] = (h16)v;
        }
    } else {
        // q-init: q[n] = emb[Z[n]] (16 atoms / block, coalesced float4 pairs)
        int a = (b - 3177) * 16 + (threadIdx.x >> 4);
        int f0 = (threadIdx.x & 15) * 8;
        if (a < NA) {
            const float* src = emb + (size_t)Zt[a] * 128 + f0;
            float4 v0 = *(const float4*)src;
            float4 v1 = *(const float4*)(src + 4);
            *(float4*)&q[(size_t)a * 128 + f0] = v0;
            *(float4*)&q[(size_t)a * 128 + f0 + 4] = v1;
        }
    }
}

// ====== iteration-0 interaction MLP, Z-DEDUPED ======
// x at iteration 0 is a pure function of Z (x = MLP(emb[Z])), and Z has only
// 101 distinct values. Compute x01z[z][128][2] for z=0..100 — 7 blocks
// instead of 625, and the edge<false> gather table shrinks 5MB -> 51.7KB
// (guaranteed L1/L2 resident). Bit-identical x values.
__global__ __launch_bounds__(256) void intmlp0z_kernel(
    const float* __restrict__ emb,
    const h16* __restrict__ W1t, const float* __restrict__ b1,
    const h16* __restrict__ W2t, const float* __restrict__ b2, h16* __restrict__ x01z)
{
    __shared__ h16 Hs[16 * 136];
    const int tid = threadIdx.x;
    const int wave = tid >> 6, lane = tid & 63;
    const int ar = lane & 15, kg = lane >> 4;
    const int row0 = blockIdx.x * 16;

    const int zr = min(row0 + ar, 100);
    f32x4 a1[2] = {};
    for (int ks = 0; ks < 128; ks += 32) {
        int k = ks + kg * 8;
        half8 af = f32x8_to_h8(emb + (size_t)zr * 128 + k);
#pragma unroll
        for (int tt = 0; tt < 2; ++tt) {
            int t = wave * 2 + tt;
            half8 bf = *(const half8*)&W1t[(size_t)(t * 16 + ar) * 128 + k];
            a1[tt] = __builtin_amdgcn_mfma_f32_16x16x32_f16(af, bf, a1[tt], 0, 0, 0);
        }
    }
#pragma unroll
    for (int tt = 0; tt < 2; ++tt) {
        int col = (wave * 2 + tt) * 16 + ar;
        float bb = b1[col];
#pragma unroll
        for (int r = 0; r < 4; ++r)
            Hs[(kg * 4 + r) * 136 + col] = (h16)silu(a1[tt][r] + bb);
    }
    __syncthreads();
    f32x4 a2[6] = {};
    for (int ks = 0; ks < 128; ks += 32) {
        int k = ks + kg * 8;
        half8 af = *(const half8*)&Hs[ar * 136 + k];
#pragma unroll
        for (int tt = 0; tt < 6; ++tt) {
            int t = wave * 6 + tt;
            half8 bf = *(const half8*)&W2t[(size_t)(t * 16 + ar) * 128 + k];
            a2[tt] = __builtin_amdgcn_mfma_f32_16x16x32_f16(af, bf, a2[tt], 0, 0, 0);
        }
    }
#pragma unroll
    for (int tt = 0; tt < 6; ++tt) {
        int col = (wave * 6 + tt) * 16 + ar;
        if (col < 256) {                         // x2 (col>=256) unused at iter 0
            float bb = b2[col];
            int slot = col >> 7, ff = col & 127;
#pragma unroll
            for (int r = 0; r < 4; ++r) {
                int z = row0 + kg * 4 + r;
                if (z <= 100)
                    x01z[((size_t)z * 128 + ff) * 2 + slot] = (h16)(a2[tt][r] + bb);
            }
        }
    }
}

// ====== edge kernel: round-2 proven loop (control: do not restructure) ======
// HAS_MU=true: identical to round 7 (73.5-74 us, the measured equilibrium;
// 6 structural variants all lost to it). HAS_MU=false: gather index comes
// free from the ed-row payload (element 22 = Zj) and the table is the
// 51.7KB z-table — zero HBM gather misses, no idx_j stream.
template<bool HAS_MU>
__global__ __launch_bounds__(128, 4) void edge_kernel(
    const h16* __restrict__ ed, const h16* __restrict__ fwt,
    const int* __restrict__ row_start, const int* __restrict__ idx_j,
    const h16* __restrict__ gat, const float* __restrict__ mup,
    float* __restrict__ mun, h16* __restrict__ mu16n, float* __restrict__ q)
{
    const int n = blockIdx.x, f = threadIdx.x;
    half8 FA[3], FB[3], FC[3];
    {
        const half8* pa = (const half8*)(fwt + (size_t)f * 32);
        const half8* pb = (const half8*)(fwt + (size_t)(128 + f) * 32);
#pragma unroll
        for (int r = 0; r < 3; ++r) { FA[r] = pa[r]; FB[r] = pb[r]; }
        if (HAS_MU) {
            const half8* pc = (const half8*)(fwt + (size_t)(256 + f) * 32);
#pragma unroll
            for (int r = 0; r < 3; ++r) FC[r] = pc[r];
        }
    }
    asm volatile("" : "+v"(FA[0]), "+v"(FA[1]), "+v"(FA[2]),
                      "+v"(FB[0]), "+v"(FB[1]), "+v"(FB[2]));
    if (HAS_MU)
        asm volatile("" : "+v"(FC[0]), "+v"(FC[1]), "+v"(FC[2]));

    half2v fa[12], fb[12], fc[12];
    *(half8*)&fa[0] = FA[0]; *(half8*)&fa[4] = FA[1]; *(half8*)&fa[8] = FA[2];
    *(half8*)&fb[0] = FB[0]; *(half8*)&fb[4] = FB[1]; *(half8*)&fb[8] = FB[2];
    if (HAS_MU) {
        *(half8*)&fc[0] = FC[0]; *(half8*)&fc[4] = FC[1]; *(half8*)&fc[8] = FC[2];
    }

    float accq = 0.f, am0 = 0.f, am1 = 0.f, am2 = 0.f;
    const int e0 = row_start[n], e1 = row_start[n + 1];

    if (HAS_MU) {
        const h16* xmf = gat + (size_t)f * 6;
        if (e0 < e1) {
            int j = idx_j[e0];
            const unsigned* gp = (const unsigned*)(xmf + (size_t)j * 768);
            unsigned g0n = gp[0], g1n = gp[1], g2n = gp[2];
            const h16* pb8 = ed + (size_t)e0 * 32;
            half8 p0n = *(const half8*)pb8;
            half8 p1n = *(const half8*)(pb8 + 8);
            half8 p2n = *(const half8*)(pb8 + 16);
            float4 dn = *(const float4*)(pb8 + 24);
            for (int e = e0; e < e1; ++e) {
                unsigned g0 = g0n, g1 = g1n, g2 = g2n;
                half8 p0 = p0n, p1 = p1n, p2 = p2n;
                float4 g = dn;
                int ep = (e + 1 < e1) ? e + 1 : e;
                int j2 = idx_j[ep];
                const unsigned* gp2 = (const unsigned*)(xmf + (size_t)j2 * 768);
                g0n = gp2[0]; g1n = gp2[1]; g2n = gp2[2];
                const h16* pb2 = ed + (size_t)ep * 32;
                p0n = *(const half8*)pb2;
                p1n = *(const half8*)(pb2 + 8);
                p2n = *(const half8*)(pb2 + 16);
                dn = *(const float4*)(pb2 + 24);
                half2v pr[12];
                *(half8*)&pr[0] = p0; *(half8*)&pr[4] = p1; *(half8*)&pr[8] = p2;
                half2v A0 = {(h16)0.f, (h16)0.f}, A1 = A0, A2 = A0;
#pragma unroll
                for (int r = 0; r < 11; ++r) {
                    A0 = pr[r] * fa[r] + A0;
                    A1 = pr[r] * fb[r] + A1;
                    A2 = pr[r] * fc[r] + A2;
                }
                float w0 = (float)A0[0] + (float)A0[1];
                float w1 = (float)A1[0] + (float)A1[1];
                float w2 = (float)A2[0] + (float)A2[1];
                half2v h01 = __builtin_bit_cast(half2v, g0);
                half2v h23 = __builtin_bit_cast(half2v, g1);
                half2v h45 = __builtin_bit_cast(half2v, g2);
                float x0 = (float)h01[0], x1 = (float)h01[1];
                accq = fmaf(w0, x0, accq);
                float xw1 = w1 * x1;
                float x2 = (float)h23[0];
                float xw2 = w2 * x2;
                am0 += xw1 * g.x + xw2 * (float)h23[1];
                am1 += xw1 * g.y + xw2 * (float)h45[0];
                am2 += xw1 * g.z + xw2 * (float)h45[1];
            }
        }
    } else {
        const h16* xmf = gat + (size_t)f * 2;
        if (e0 < e1) {
            const h16* pb8 = ed + (size_t)e0 * 32;
            half8 p0n = *(const half8*)pb8;
            half8 p1n = *(const half8*)(pb8 + 8);
            half8 p2n = *(const half8*)(pb8 + 16);
            float4 dn = *(const float4*)(pb8 + 24);
            unsigned short z0 = __builtin_bit_cast(unsigned short, (h16)p2n[6]);
            unsigned g0n = *(const unsigned*)(xmf + (size_t)z0 * 256);
            for (int e = e0; e < e1; ++e) {
                unsigned g0 = g0n;
                half8 p0 = p0n, p1 = p1n, p2 = p2n;
                float4 g = dn;
                int ep = (e + 1 < e1) ? e + 1 : e;
                const h16* pb2 = ed + (size_t)ep * 32;
                p0n = *(const half8*)pb2;
                p1n = *(const half8*)(pb2 + 8);
                p2n = *(const half8*)(pb2 + 16);
                dn = *(const float4*)(pb2 + 24);
                unsigned short z2 = __builtin_bit_cast(unsigned short, (h16)p2n[6]);
                g0n = *(const unsigned*)(xmf + (size_t)z2 * 256);
                half2v pr[12];
                *(half8*)&pr[0] = p0; *(half8*)&pr[4] = p1; *(half8*)&pr[8] = p2;
                half2v A0 = {(h16)0.f, (h16)0.f}, A1 = A0;
#pragma unroll
                for (int r = 0; r < 11; ++r) {
                    A0 = pr[r] * fa[r] + A0;
                    A1 = pr[r] * fb[r] + A1;
                }
                float w0 = (float)A0[0] + (float)A0[1];
                float w1 = (float)A1[0] + (float)A1[1];
                half2v h01 = __builtin_bit_cast(half2v, g0);
                float x0 = (float)h01[0], x1 = (float)h01[1];
                accq = fmaf(w0, x0, accq);
                float xw1 = w1 * x1;
                am0 = fmaf(xw1, g.x, am0);
                am1 = fmaf(xw1, g.y, am1);
                am2 = fmaf(xw1, g.z, am2);
            }
        }
    }

    q[(size_t)n * FD + f] += accq;
    size_t b = (size_t)n * 384;
    float m0 = (HAS_MU ? mup[b + f] : 0.f) + am0;
    float m1 = (HAS_MU ? mup[b + 128 + f] : 0.f) + am1;
    float m2 = (HAS_MU ? mup[b + 256 + f] : 0.f) + am2;
    mun[b + f] = m0; mun[b + 128 + f] = m1; mun[b + 256 + f] = m2;
    mu16n[b + f] = (h16)m0; mu16n[b + 128 + f] = (h16)m1; mu16n[b + 256 + f] = (h16)m2;
}

// ====== fused mixing (+ optional next-iteration interaction MLP) ======
__global__ __launch_bounds__(256) void mixint_kernel(
    const h16* __restrict__ mu16n, const h16* __restrict__ WmuT,
    const h16* __restrict__ W1t, const float* __restrict__ b1,
    const h16* __restrict__ W2t, const float* __restrict__ b2,
    float* __restrict__ q, float* __restrict__ mu, h16* __restrict__ xmw,
    const h16* __restrict__ nW1t, const float* __restrict__ nb1,
    const h16* __restrict__ nW2t, const float* __restrict__ nb2)
{
    __shared__ __align__(16) h16 MM[48 * 264];   // reused as XMP in nW branch
    __shared__ h16 CT[16 * 264];
    __shared__ h16 Hs[16 * 136];
    __shared__ h16 XM[16 * 392];
    const int tid = threadIdx.x;
    const int wave = tid >> 6, lane = tid & 63;
    const int ar = lane & 15, kg = lane >> 4;
    const size_t row0 = (size_t)blockIdx.x * 16;

    {
        f32x4 acc[3][4] = {};
        int aloc[3], dloc[3];
#pragma unroll
        for (int rt = 0; rt < 3; ++rt) {
            int rr = rt * 16 + ar;
            aloc[rt] = rr / 3;
            dloc[rt] = rr - 3 * aloc[rt];
        }
        for (int ks = 0; ks < 128; ks += 32) {
            int k = ks + kg * 8;
            half8 afr[3];
#pragma unroll
            for (int rt = 0; rt < 3; ++rt)
                afr[rt] = *(const half8*)&mu16n[(row0 + aloc[rt]) * 384 + dloc[rt] * 128 + k];
#pragma unroll
            for (int ct = 0; ct < 4; ++ct) {
                int cc = wave * 4 + ct;
                half8 bf = *(const half8*)&WmuT[(size_t)(cc * 16 + ar) * 128 + k];
#pragma unroll
                for (int rt = 0; rt < 3; ++rt)
                    acc[rt][ct] = __builtin_amdgcn_mfma_f32_16x16x32_f16(afr[rt], bf, acc[rt][ct], 0, 0, 0);
            }
        }
#pragma unroll
        for (int rt = 0; rt < 3; ++rt)
#pragma unroll
            for (int ct = 0; ct < 4; ++ct) {
                int col = (wave * 4 + ct) * 16 + ar;
#pragma unroll
                for (int r = 0; r < 4; ++r)
                    MM[(rt * 16 + kg * 4 + r) * 264 + col] = (h16)acc[rt][ct][r];
            }
    }
    __syncthreads();

    float qv[8];   // carried in registers to the epilogue (same (a,ff) mapping)
    {
        int a = tid >> 4, fi = (tid & 15) * 8;
        const float* qp = q + (row0 + a) * 128 + fi;
        float4 q0 = *(const float4*)qp;
        float4 q1 = *(const float4*)(qp + 4);
        qv[0] = q0.x; qv[1] = q0.y; qv[2] = q0.z; qv[3] = q0.w;
        qv[4] = q1.x; qv[5] = q1.y; qv[6] = q1.z; qv[7] = q1.w;
#pragma unroll
        for (int jj = 0; jj < 8; ++jj) {
            int ff = fi + jj;
            float v0 = (float)MM[(a * 3 + 0) * 264 + ff];
            float v1 = (float)MM[(a * 3 + 1) * 264 + ff];
            float v2 = (float)MM[(a * 3 + 2) * 264 + ff];
            CT[a * 264 + 128 + ff] = (h16)sqrtf(v0 * v0 + v1 * v1 + v2 * v2 + 1e-8f);
            CT[a * 264 + ff] = (h16)qv[jj];
        }
    }
    __syncthreads();

    {
        f32x4 a1[2] = {};
        for (int ks = 0; ks < 256; ks += 32) {
            int k = ks + kg * 8;
            half8 af = *(const half8*)&CT[ar * 264 + k];
#pragma unroll
            for (int tt = 0; tt < 2; ++tt) {
                int t = wave * 2 + tt;
                half8 bf = *(const half8*)&W1t[(size_t)(t * 16 + ar) * 256 + k];
                a1[tt] = __builtin_amdgcn_mfma_f32_16x16x32_f16(af, bf, a1[tt], 0, 0, 0);
            }
        }
#pragma unroll
        for (int tt = 0; tt < 2; ++tt) {
            int col = (wave * 2 + tt) * 16 + ar;
            float bb = b1[col];
#pragma unroll
            for (int r = 0; r < 4; ++r)
                Hs[(kg * 4 + r) * 136 + col] = (h16)silu(a1[tt][r] + bb);
        }
    }
    __syncthreads();

    {
        f32x4 a2[6] = {};
        for (int ks = 0; ks < 128; ks += 32) {
            int k = ks + kg * 8;
            half8 af = *(const half8*)&Hs[ar * 136 + k];
#pragma unroll
            for (int tt = 0; tt < 6; ++tt) {
                int t = wave * 6 + tt;
                half8 bf = *(const half8*)&W2t[(size_t)(t * 16 + ar) * 128 + k];
                a2[tt] = __builtin_amdgcn_mfma_f32_16x16x32_f16(af, bf, a2[tt], 0, 0, 0);
            }
        }
#pragma unroll
        for (int tt = 0; tt < 6; ++tt) {
            int col = (wave * 6 + tt) * 16 + ar;
            float bb = b2[col];
#pragma unroll
            for (int r = 0; r < 4; ++r)
                XM[(kg * 4 + r) * 392 + col] = (h16)(a2[tt][r] + bb);
        }
    }
    __syncthreads();

    h16 mh[24];   // per-thread staged mu16, flushed in nW branch
    {
        int a = tid >> 4, fi = (tid & 15) * 8;
        size_t n = row0 + a;
#pragma unroll
        for (int jj = 0; jj < 8; ++jj) {
            int ff = fi + jj;
            float dq  = (float)XM[a * 392 + ff];
            float dm  = (float)XM[a * 392 + 128 + ff];
            float dqm = (float)XM[a * 392 + 256 + ff];
            float v0 = (float)MM[(a * 3 + 0) * 264 + ff], w0 = (float)MM[(a * 3 + 0) * 264 + 128 + ff];
            float v1 = (float)MM[(a * 3 + 1) * 264 + ff], w1 = (float)MM[(a * 3 + 1) * 264 + 128 + ff];
            float v2 = (float)MM[(a * 3 + 2) * 264 + ff], w2 = (float)MM[(a * 3 + 2) * 264 + 128 + ff];
            float sv = v0 * w0 + v1 * w1 + v2 * w2;
            float qn = qv[jj] + dq + dqm * sv;
            q[n * 128 + ff] = qn;
            CT[a * 264 + ff] = (h16)qn;
            size_t b = n * 384 + ff;
            float m0 = mu[b] + dm * w0;
            float m1 = mu[b + 128] + dm * w1;
            float m2 = mu[b + 256] + dm * w2;
            mu[b] = m0; mu[b + 128] = m1; mu[b + 256] = m2;
            mh[jj * 3 + 0] = (h16)m0; mh[jj * 3 + 1] = (h16)m1; mh[jj * 3 + 2] = (h16)m2;
        }
    }
    if (!nW1t) return;
    __syncthreads();

    {
        f32x4 a1[2] = {};
        for (int ks = 0; ks < 128; ks += 32) {
            int k = ks + kg * 8;
            half8 af = *(const half8*)&CT[ar * 264 + k];
#pragma unroll
            for (int tt = 0; tt < 2; ++tt) {
                int t = wave * 2 + tt;
                half8 bf = *(const half8*)&nW1t[(size_t)(t * 16 + ar) * 128 + k];
                a1[tt] = __builtin_amdgcn_mfma_f32_16x16x32_f16(af, bf, a1[tt], 0, 0, 0);
            }
        }
#pragma unroll
        for (int tt = 0; tt < 2; ++tt) {
            int col = (wave * 2 + tt) * 16 + ar;
            float bb = nb1[col];
#pragma unroll
            for (int r = 0; r < 4; ++r)
                Hs[(kg * 4 + r) * 136 + col] = (h16)silu(a1[tt][r] + bb);
        }
        __syncthreads();
        f32x4 a2[6] = {};
        for (int ks = 0; ks < 128; ks += 32) {
            int k = ks + kg * 8;
            half8 af = *(const half8*)&Hs[ar * 136 + k];
#pragma unroll
            for (int tt = 0; tt < 6; ++tt) {
                int t = wave * 6 + tt;
                half8 bf = *(const half8*)&nW2t[(size_t)(t * 16 + ar) * 128 + k];
                a2[tt] = __builtin_amdgcn_mfma_f32_16x16x32_f16(af, bf, a2[tt], 0, 0, 0);
            }
        }
        h16* XMP = MM;
#pragma unroll
        for (int tt = 0; tt < 6; ++tt) {
            int col = (wave * 6 + tt) * 16 + ar;
            float bb = nb2[col];
            int slot = col >> 7, ff = col & 127;
#pragma unroll
            for (int r = 0; r < 4; ++r)
                XMP[((kg * 4 + r) * 128 + ff) * 6 + slot] = (h16)(a2[tt][r] + bb);
        }
        {
            int a = tid >> 4, fi = (tid & 15) * 8;
#pragma unroll
            for (int jj = 0; jj < 8; ++jj)
#pragma unroll
                for (int s = 0; s < 3; ++s)
                    XMP[(a * 128 + fi + jj) * 6 + 3 + s] = mh[jj * 3 + s];
        }
        __syncthreads();
        {
            const uint4* src = (const uint4*)MM;
            uint4* dst = (uint4*)(xmw + row0 * 768);
#pragma unroll
            for (int i = 0; i < 6; ++i)
                dst[tid + i * 256] = src[tid + i * 256];
        }
    }
}

// ====== launch ======
extern "C" void kernel_launch(void* const* d_in, const int* in_sizes, int n_in,
                              void* d_out, int out_size, void* d_ws, size_t ws_size,
                              hipStream_t stream)
{
    const int*   Z       = (const int*)d_in[0];
    const float* R       = (const float*)d_in[1];
    const int*   idx_i   = (const int*)d_in[2];
    const int*   idx_j   = (const int*)d_in[3];
    const float* offsets = (const float*)d_in[4];
    const float* emb     = (const float*)d_in[5];
    const float* filt_W  = (const float*)d_in[6];
    const float* filt_b  = (const float*)d_in[7];
    const float* int_W1  = (const float*)d_in[8];
    const float* int_b1  = (const float*)d_in[9];
    const float* int_W2  = (const float*)d_in[10];
    const float* int_b2  = (const float*)d_in[11];
    const float* mix_Wmu = (const float*)d_in[12];
    const float* mix_W1  = (const float*)d_in[13];
    const float* mix_b1  = (const float*)d_in[14];
    const float* mix_W2  = (const float*)d_in[15];
    const float* mix_b2  = (const float*)d_in[16];

    float* q_out  = (float*)d_out;
    float* mu_out = (float*)d_out + (size_t)NA * FD;

    char* base = (char*)d_ws;
    size_t o = 0;
    auto alloc = [&](size_t bytes) -> void* {
        void* p = base + o;
        o += (bytes + 255) & ~(size_t)255;
        return p;
    };
    h16*   ed     = (h16*)alloc((size_t)NE * 32 * 2);        // merged ph+zj+dir, 64B/edge
    h16*   xm     = (h16*)alloc((size_t)NA * 128 * 6 * 2);   // packed x+mu for edge gather
    h16*   x01z   = (h16*)alloc((size_t)101 * 128 * 2 * 2);  // per-Z (x0,x1) table, 51.7KB
    h16*   mu16p  = (h16*)alloc((size_t)NA * 384 * 2);       // planar pre-mix mu
    float* mu_ws  = (float*)alloc((size_t)NA * 384 * 4);
    h16*   W1t    = (h16*)alloc((size_t)3 * 128 * 128 * 2);
    h16*   W2t    = (h16*)alloc((size_t)3 * 384 * 128 * 2);
    h16*   WmuT   = (h16*)alloc((size_t)3 * 256 * 128 * 2);
    h16*   mW1t   = (h16*)alloc((size_t)3 * 128 * 256 * 2);
    h16*   mW2t   = (h16*)alloc((size_t)3 * 384 * 128 * 2);
    h16*   fwt    = (h16*)alloc((size_t)384 * 32 * 2);
    int*   row_st = (int*)alloc((size_t)(NA + 1) * 4);

    setup_kernel<<<3802, 256, 0, stream>>>(R, idx_i, idx_j, offsets, Z, emb, q_out,
                                           ed, row_st,
                                           int_W1, int_W2, mix_Wmu, mix_W1, mix_W2,
                                           W1t, W2t, WmuT, mW1t, mW2t,
                                           filt_W, filt_b, fwt);

    // iteration 0
    intmlp0z_kernel<<<7, 256, 0, stream>>>(emb, W1t, int_b1, W2t, int_b2, x01z);
    edge_kernel<false><<<NA, 128, 0, stream>>>(ed, fwt, row_st, idx_j,
                                               x01z, nullptr, mu_out, mu16p, q_out);
    mixint_kernel<<<NA / 16, 256, 0, stream>>>(
        mu16p, WmuT, mW1t, mix_b1, mW2t, mix_b2, q_out, mu_out, xm,
        W1t + 16384, int_b1 + 128, W2t + 49152, int_b2 + 384);

    // iteration 1
    edge_kernel<true><<<NA, 128, 0, stream>>>(ed, fwt, row_st, idx_j,
                                              xm, mu_out, mu_ws, mu16p, q_out);
    mixint_kernel<<<NA / 16, 256, 0, stream>>>(
        mu16p, WmuT + 32768, mW1t + 32768, mix_b1 + 128, mW2t + 49152, mix_b2 + 384,
        q_out, mu_ws, xm,
        W1t + 32768, int_b1 + 256, W2t + 98304, int_b2 + 768);

    // iteration 2
    edge_kernel<true><<<NA, 128, 0, stream>>>(ed, fwt, row_st, idx_j,
                                              xm, mu_ws, mu_out, mu16p, q_out);
    mixint_kernel<<<NA / 16, 256, 0, stream>>>(
        mu16p, WmuT + 65536, mW1t + 65536, mix_b1 + 256, mW2t + 98304, mix_b2 + 768,
        q_out, mu_out, xm,
        nullptr, nullptr, nullptr, nullptr);
}